// Round 7
// baseline (2142.277 us; speedup 1.0000x reference)
//
#include <hip/hip_runtime.h>
#include <stdint.h>
#include <math.h>

typedef __bf16 bf16_t;
typedef float f32x4 __attribute__((ext_vector_type(4)));
typedef __bf16 bf16x8 __attribute__((ext_vector_type(8)));
typedef __bf16 bf16x4 __attribute__((ext_vector_type(4)));

#define D_ 1024
#define M_ 8192

// ======== DIAGNOSTIC ROUND: rep-loops amplify kernels into rocprof top-5 ====
#define REP_ATTN 4
#define REP_QKV 8
#define REP_PROJ 12

__device__ __forceinline__ f32x4 mfma16(bf16x8 a, bf16x8 b, f32x4 c) {
  return __builtin_amdgcn_mfma_f32_16x16x32_bf16(a, b, c, 0, 0, 0);
}

__device__ __forceinline__ void gl_lds16(const bf16_t* g, bf16_t* l) {
  __builtin_amdgcn_global_load_lds(
      (const __attribute__((address_space(1))) unsigned int*)g,
      (__attribute__((address_space(3))) unsigned int*)l, 16, 0, 0);
}

// ---------------- all fp32 -> bf16 converts in ONE launch ----------------
__global__ __launch_bounds__(256) void cvt_all(
    const float* __restrict__ x,
    const float* __restrict__ w0, const float* __restrict__ w1,
    const float* __restrict__ w2, const float* __restrict__ w3,
    bf16_t* __restrict__ xb,
    bf16_t* __restrict__ d0, bf16_t* __restrict__ d1,
    bf16_t* __restrict__ d2, bf16_t* __restrict__ d3) {
  int b = blockIdx.x;
  const float* s;
  bf16_t* d;
  int i;
  if (b < 4096) {
    s = x; d = xb; i = b * 256 + threadIdx.x;
  } else {
    int g = b - 4096;
    int which = g >> 9;
    s = which == 0 ? w0 : which == 1 ? w1 : which == 2 ? w2 : w3;
    d = which == 0 ? d0 : which == 1 ? d1 : which == 2 ? d2 : d3;
    i = (g & 511) * 256 + threadIdx.x;
  }
  const f32x4* p = (const f32x4*)(s + (size_t)i * 8);
  f32x4 a = p[0], bb = p[1];
  bf16x8 o;
  o[0] = (bf16_t)a.x; o[1] = (bf16_t)a.y; o[2] = (bf16_t)a.z; o[3] = (bf16_t)a.w;
  o[4] = (bf16_t)bb.x; o[5] = (bf16_t)bb.y; o[6] = (bf16_t)bb.z; o[7] = (bf16_t)bb.w;
  *(bf16x8*)(d + (size_t)i * 8) = o;
}

// ================= QKV: 256x256 8-phase pipelined GEMM =================
#define LDSB(e) (*(const bf16x8*)(Sm + (e)))

#define STG_AH(b, h, kt)                                                      \
  {                                                                           \
    gl_lds16(A + sA + (h) * 131072 + (kt) * 64,                               \
             Sm + (b) * 32768 + (h) * 8192 + tid * 8);                        \
    gl_lds16(A + sA + (h) * 131072 + 65536 + (kt) * 64,                       \
             Sm + (b) * 32768 + (h) * 8192 + 4096 + tid * 8);                 \
  }
#define STG_BH(b, h, kt)                                                      \
  {                                                                           \
    gl_lds16(Wsel + sB + (h) * 131072 + (kt) * 64,                            \
             Sm + (b) * 32768 + 16384 + (h) * 8192 + tid * 8);                \
    gl_lds16(Wsel + sB + (h) * 131072 + 65536 + (kt) * 64,                    \
             Sm + (b) * 32768 + 16384 + (h) * 8192 + 4096 + tid * 8);         \
  }

#define QUAD(B, S0, S1, S2, S3)                                               \
  {                                                                           \
    const int bb = (B) * 32768;                                               \
    _Pragma("unroll") for (int q = 0; q < 4; ++q) {                           \
      if (q == 0) {                                                           \
        _Pragma("unroll") for (int fn = 0; fn < 4; ++fn) {                    \
          bfr[fn][0] = LDSB(bb + bBase + fn * 1024);                          \
          bfr[fn][1] = LDSB(bb + bBase + fn * 1024 + 32);                     \
        }                                                                     \
      }                                                                       \
      bf16x8 af[2][2];                                                        \
      _Pragma("unroll") for (int mi = 0; mi < 2; ++mi) {                      \
        af[mi][0] = LDSB(bb + aBase + (2 * q + mi) * 1024);                   \
        af[mi][1] = LDSB(bb + aBase + (2 * q + mi) * 1024 + 32);              \
      }                                                                       \
      if (q == 0) { S0; } else if (q == 1) { S1; }                            \
      else if (q == 2) { S2; } else { S3; }                                   \
      __builtin_amdgcn_s_barrier();                                           \
      __builtin_amdgcn_s_setprio(1);                                          \
      _Pragma("unroll") for (int mi = 0; mi < 2; ++mi)                        \
      _Pragma("unroll") for (int fn = 0; fn < 4; ++fn) {                      \
        acc[2 * q + mi][fn] =                                                 \
            mfma16(af[mi][0], bfr[fn][0], acc[2 * q + mi][fn]);               \
        acc[2 * q + mi][fn] =                                                 \
            mfma16(af[mi][1], bfr[fn][1], acc[2 * q + mi][fn]);               \
      }                                                                       \
      __builtin_amdgcn_s_setprio(0);                                          \
      __builtin_amdgcn_s_barrier();                                           \
    }                                                                         \
  }

__global__ __launch_bounds__(512) void gemm_qkv8(
    const bf16_t* __restrict__ A,
    const bf16_t* __restrict__ Wq, const bf16_t* __restrict__ Wk,
    const bf16_t* __restrict__ Wv,
    const float* __restrict__ bq, const float* __restrict__ bk,
    const float* __restrict__ bv,
    bf16_t* __restrict__ Oq, bf16_t* __restrict__ Ok, bf16_t* __restrict__ Ov) {
  __shared__ bf16_t Sm[65536];  // 128 KiB

  const int tid = threadIdx.x;
  const int l = tid & 63, w = tid >> 6;
  const int wm = w >> 2, wn = w & 3;
  const int lr = l & 15, lg = l >> 4;

  int wg = blockIdx.x;
  int nid = (wg & 7) * 48 + (wg >> 3);
  int bm = nid & 31, bnid = nid >> 5;
  int which = bnid >> 2;
  const bf16_t* Wsel = which == 0 ? Wq : (which == 1 ? Wk : Wv);
  const float* bias = which == 0 ? bq : (which == 1 ? bk : bv);
  bf16_t* O = which == 0 ? Oq : (which == 1 ? Ok : Ov);
  const float scale = which == 0 ? 0.18033688f : 1.0f;
  const int m0 = bm * 256, n0 = (bnid & 3) * 256;

  const int scol = ((l & 7) ^ (((l >> 5) & 1) << 1)) * 8;
  const int sA = (m0 + w * 8 + (l >> 3)) * 1024 + scol;
  const int sB = (n0 + w * 8 + (l >> 3)) * 1024 + scol;

  const int eCol = (lg * 8) ^ ((lr & 4) << 2);
  const int aBase = wm * 8192 + lr * 64 + eCol;
  const int bBase = 16384 + (wn >> 1) * 8192 + ((wn & 1) * 64 + lr) * 64 + eCol;

  for (int rep = 0; rep < REP_QKV; ++rep) {
    __syncthreads();
    f32x4 acc[8][4] = {};
    bf16x8 bfr[4][2];

    STG_AH(0, 0, 0) STG_AH(0, 1, 0) STG_BH(0, 0, 0) STG_BH(0, 1, 0)
    STG_BH(1, 0, 1) STG_BH(1, 1, 1) STG_AH(1, 0, 1)
    asm volatile("s_waitcnt vmcnt(6)" ::: "memory");
    __builtin_amdgcn_sched_barrier(0);
    __builtin_amdgcn_s_barrier();

    for (int i = 0; i < 8; ++i) {
      const bool st = (i < 7);
      const int k2 = 2 * i + 2, k3 = 2 * i + 3;
      QUAD(0,
           STG_AH(1, 1, 2 * i + 1),
           if (st) STG_BH(0, 0, k2),
           if (st) STG_BH(0, 1, k2),
           if (st) STG_AH(0, 0, k2))
      if (i < 7) {
        asm volatile("s_waitcnt vmcnt(6)" ::: "memory");
      } else {
        asm volatile("s_waitcnt vmcnt(0)" ::: "memory");
      }
      __builtin_amdgcn_sched_barrier(0);
      QUAD(1,
           if (st) STG_AH(0, 1, k2),
           if (st) STG_BH(1, 0, k3),
           if (st) STG_BH(1, 1, k3),
           if (st) STG_AH(1, 0, k3))
      if (i < 7) {
        asm volatile("s_waitcnt vmcnt(6)" ::: "memory");
        __builtin_amdgcn_sched_barrier(0);
      }
    }

#pragma unroll
    for (int fn = 0; fn < 4; ++fn) {
      int col = n0 + wn * 64 + fn * 16 + lr;
      float bb2 = bias[col];
#pragma unroll
      for (int fm = 0; fm < 8; ++fm) {
        int row = m0 + wm * 128 + fm * 16 + lg * 4;
        bf16_t* op = O + (size_t)row * 1024 + col;
#pragma unroll
        for (int r = 0; r < 4; ++r)
          op[(size_t)r * 1024] = (bf16_t)((acc[fm][fn][r] + bb2) * scale);
      }
    }
  }
}

// ---------------- shared 128x128x(K=1024) bf16 GEMM core ----------------
__device__ __forceinline__ void gemm_core(const bf16_t* __restrict__ A,
                                          const bf16_t* __restrict__ W,
                                          int m0, int n0,
                                          bf16_t* As, bf16_t* Bs,
                                          f32x4 acc[4][4]) {
  const int t = threadIdx.x;
  const int l = t & 63, w = t >> 6;
  const int wr = w >> 1, wc = w & 1;
  const int lr = l & 15, lg = l >> 4;
  const int srow = t >> 2;
  const int scol = (t & 3) * 8;
  const bf16_t* gA0 = A + (size_t)(m0 + srow) * D_ + scol;
  const bf16_t* gA1 = A + (size_t)(m0 + 64 + srow) * D_ + scol;
  const bf16_t* gB0 = W + (size_t)(n0 + srow) * D_ + scol;
  const bf16_t* gB1 = W + (size_t)(n0 + 64 + srow) * D_ + scol;

  for (int k0 = 0; k0 < D_; k0 += 32) {
    gl_lds16(gA0 + k0, As + t * 8);
    gl_lds16(gA1 + k0, As + 2048 + t * 8);
    gl_lds16(gB0 + k0, Bs + t * 8);
    gl_lds16(gB1 + k0, Bs + 2048 + t * 8);
    __syncthreads();
    bf16x8 af[4], bfr[4];
#pragma unroll
    for (int i = 0; i < 4; ++i)
      af[i] = *(const bf16x8*)(As + (wr * 64 + i * 16 + lr) * 32 + lg * 8);
#pragma unroll
    for (int i = 0; i < 4; ++i)
      bfr[i] = *(const bf16x8*)(Bs + (wc * 64 + i * 16 + lr) * 32 + lg * 8);
#pragma unroll
    for (int mi = 0; mi < 4; ++mi)
#pragma unroll
      for (int ni = 0; ni < 4; ++ni)
        acc[mi][ni] = mfma16(af[mi], bfr[ni], acc[mi][ni]);
    __syncthreads();
  }
}

// ---------------- proj GEMM: out fp32 = acc + bo + x (residual) ----------------
__global__ __launch_bounds__(256) void gemm_proj(
    const bf16_t* __restrict__ A, const bf16_t* __restrict__ W,
    const float* __restrict__ bias, const float* __restrict__ xres,
    float* __restrict__ O) {
  __shared__ bf16_t As[128 * 32], Bs[128 * 32];
  int m0 = blockIdx.y * 128, n0 = blockIdx.x * 128;
  int t = threadIdx.x, l = t & 63, w = t >> 6;
  int wr = w >> 1, wc = w & 1, lr = l & 15, lg = l >> 4;
  for (int rep = 0; rep < REP_PROJ; ++rep) {
    __syncthreads();
    f32x4 acc[4][4] = {};
    gemm_core(A, W, m0, n0, As, Bs, acc);
#pragma unroll
    for (int mi = 0; mi < 4; ++mi) {
#pragma unroll
      for (int ni = 0; ni < 4; ++ni) {
        int col = n0 + wc * 64 + ni * 16 + lr;
        float bb = bias[col];
        int row = m0 + wr * 64 + mi * 16 + lg * 4;
#pragma unroll
        for (int r = 0; r < 4; ++r) {
          size_t idx = (size_t)(row + r) * D_ + col;
          O[idx] = acc[mi][ni][r] + bb + xres[idx];
        }
      }
    }
  }
}

// ---------------- V transpose via LDS tile ----------------
__global__ __launch_bounds__(256) void transpose_v(const bf16_t* __restrict__ V,
                                                   bf16_t* __restrict__ Vt) {
  __shared__ float sT[128 * 33];
  int bh = blockIdx.x >> 3, st = blockIdx.x & 7;
  int s0 = st * 128;
  int t = threadIdx.x;
  const bf16_t* src = V + (size_t)bh * 65536 + (size_t)s0 * 64;
  int li = t >> 3, lc = t & 7;
#pragma unroll
  for (int p = 0; p < 4; ++p) {
    int row = p * 32 + li;
    f32x4 v = *(const f32x4*)(src + (size_t)row * 64 + lc * 8);
    float* dst = &sT[row * 33 + lc * 4];
    dst[0] = v[0]; dst[1] = v[1]; dst[2] = v[2]; dst[3] = v[3];
  }
  __syncthreads();
  int sc = t & 15, dh0 = t >> 4;
  bf16_t* dstb = Vt + (size_t)bh * 65536;
#pragma unroll
  for (int p = 0; p < 4; ++p) {
    int dh = dh0 + p * 16;
    bf16x8 o;
#pragma unroll
    for (int j = 0; j < 8; ++j) {
      int s = sc * 8 + j;
      o[j] = ((const bf16_t*)&sT[s * 33 + (dh >> 1)])[dh & 1];
    }
    *(bf16x8*)(dstb + (size_t)dh * 1024 + s0 + sc * 8) = o;
  }
}

// ---------------- fused attention per (bh, 32-row q tile) ----------------
#define SP_STRIDE 1064
__global__ __launch_bounds__(512, 4) void attn_kernel(
    const bf16_t* __restrict__ Q, const bf16_t* __restrict__ K,
    const bf16_t* __restrict__ Vt, float* __restrict__ alpha,
    bf16_t* __restrict__ ctx) {
  __shared__ bf16_t sP[32][SP_STRIDE];
  __shared__ float sRS[8][32];
  __shared__ float sL[32];

  int id = blockIdx.x;
  int g = id >> 3, x = id & 7;
  int qt = g & 31;
  int bh = ((g >> 5) << 3) | x;
  int q0 = qt * 32;

  const bf16_t* Qb = Q + (size_t)bh * 65536;
  const bf16_t* Kb = K + (size_t)bh * 65536;
  const bf16_t* Vb = Vt + (size_t)bh * 65536;
  float* Ab = alpha + (size_t)bh * 1048576 + (size_t)q0 * 1024;

  int t = threadIdx.x, l = t & 63, w = t >> 6;
  int lr = l & 15, lg = l >> 4;

  bf16x8 qa[2][2];
#pragma unroll
  for (int mi = 0; mi < 2; ++mi)
#pragma unroll
    for (int kk = 0; kk < 2; ++kk)
      qa[mi][kk] = *(const bf16x8*)(Qb + (size_t)(q0 + mi * 16 + lr) * 64 + kk * 32 + lg * 8);

  for (int rep = 0; rep < REP_ATTN; ++rep) {
    __syncthreads();
    float pa0 = 0.f, pa1 = 0.f;
#pragma unroll
    for (int tt = 0; tt < 8; ++tt) {
      int n0 = w * 128 + tt * 16;
      bf16x8 kb0 = *(const bf16x8*)(Kb + (size_t)(n0 + lr) * 64 + lg * 8);
      bf16x8 kb1 = *(const bf16x8*)(Kb + (size_t)(n0 + lr) * 64 + 32 + lg * 8);
      f32x4 a0 = {0.f, 0.f, 0.f, 0.f};
      f32x4 a1 = {0.f, 0.f, 0.f, 0.f};
      a0 = mfma16(kb0, qa[0][0], a0);
      a0 = mfma16(kb1, qa[0][1], a0);
      a1 = mfma16(kb0, qa[1][0], a1);
      a1 = mfma16(kb1, qa[1][1], a1);
      bf16x4 w0, w1;
#pragma unroll
      for (int r = 0; r < 4; ++r) {
        float e0 = exp2f(a0[r]);
        float e1 = exp2f(a1[r]);
        pa0 += e0; pa1 += e1;
        w0[r] = (bf16_t)e0;
        w1[r] = (bf16_t)e1;
      }
      *(bf16x4*)&sP[lr][n0 + lg * 4] = w0;
      *(bf16x4*)&sP[16 + lr][n0 + lg * 4] = w1;
    }
    pa0 += __shfl_xor(pa0, 16); pa0 += __shfl_xor(pa0, 32);
    pa1 += __shfl_xor(pa1, 16); pa1 += __shfl_xor(pa1, 32);
    if (l < 16) {
      sRS[w][lr] = pa0;
      sRS[w][16 + lr] = pa1;
    }
    __syncthreads();
    if (t < 32) {
      float s = 0.f;
#pragma unroll
      for (int ww = 0; ww < 8; ++ww) s += sRS[ww][t];
      sL[t] = 1.0f / s;
    }
    __syncthreads();

    {
      int wm = w >> 2, wn = w & 3;
      f32x4 acc = {0.f, 0.f, 0.f, 0.f};
      const bf16_t* vp = Vb + (size_t)(wn * 16 + lr) * 1024 + lg * 8;
      const bf16_t* pp = &sP[wm * 16 + lr][lg * 8];
      int arow = t >> 4, acol = (t & 15) * 4;
      float inv = sL[arow];
      const bf16_t* ap = &sP[arow][acol];
      float* aout = Ab + (size_t)arow * 1024 + acol;
#pragma unroll 4
      for (int n0 = 0; n0 < 1024; n0 += 64) {
        bf16x8 ea0 = *(const bf16x8*)(pp + n0);
        bf16x8 vb0 = *(const bf16x8*)(vp + n0);
        acc = mfma16(ea0, vb0, acc);
        bf16x8 ea1 = *(const bf16x8*)(pp + n0 + 32);
        bf16x8 vb1 = *(const bf16x8*)(vp + n0 + 32);
        acc = mfma16(ea1, vb1, acc);
        bf16x4 p = *(const bf16x4*)(ap + n0);
        f32x4 o;
        o[0] = (float)p[0] * inv;
        o[1] = (float)p[1] * inv;
        o[2] = (float)p[2] * inv;
        o[3] = (float)p[3] * inv;
        __builtin_nontemporal_store(o, (f32x4*)(aout + n0));
      }
      bf16_t* cp = ctx + (size_t)bh * 65536 + (size_t)(q0 + wm * 16 + lg * 4) * 64 + wn * 16 + lr;
#pragma unroll
      for (int r = 0; r < 4; ++r)
        cp[(size_t)r * 64] = (bf16_t)(acc[r] * sL[wm * 16 + lg * 4 + r]);
    }
  }
}

// ---------------- LayerNorm in place on d_out rows ----------------
__global__ __launch_bounds__(256) void ln_kernel(float* __restrict__ io,
                                                 const float* __restrict__ gamma,
                                                 const float* __restrict__ beta) {
  int row = blockIdx.x;
  int t = threadIdx.x;
  float* p = io + (size_t)row * 1024;
  f32x4 v = *(const f32x4*)(p + t * 4);
  float s = v[0] + v[1] + v[2] + v[3];
  float s2 = v[0] * v[0] + v[1] * v[1] + v[2] * v[2] + v[3] * v[3];
#pragma unroll
  for (int off = 1; off <= 32; off <<= 1) {
    s += __shfl_xor(s, off);
    s2 += __shfl_xor(s2, off);
  }
  __shared__ float ps[4], ps2[4];
  int w = t >> 6, l = t & 63;
  if (l == 0) { ps[w] = s; ps2[w] = s2; }
  __syncthreads();
  float S = ps[0] + ps[1] + ps[2] + ps[3];
  float S2 = ps2[0] + ps2[1] + ps2[2] + ps2[3];
  float mu = S * (1.f / 1024.f);
  float var = S2 * (1.f / 1024.f) - mu * mu;
  float rs = rsqrtf(var + 1e-5f);
  f32x4 g = *(const f32x4*)(gamma + t * 4);
  f32x4 b = *(const f32x4*)(beta + t * 4);
  f32x4 o;
  o[0] = (v[0] - mu) * rs * g[0] + b[0];
  o[1] = (v[1] - mu) * rs * g[1] + b[1];
  o[2] = (v[2] - mu) * rs * g[2] + b[2];
  o[3] = (v[3] - mu) * rs * g[3] + b[3];
  *(f32x4*)(p + t * 4) = o;
}

extern "C" void kernel_launch(void* const* d_in, const int* in_sizes, int n_in,
                              void* d_out, int out_size, void* d_ws, size_t ws_size,
                              hipStream_t stream) {
  const float* x = (const float*)d_in[0];
  const float* Wq = (const float*)d_in[1];
  const float* bq = (const float*)d_in[2];
  const float* Wk = (const float*)d_in[3];
  const float* bk = (const float*)d_in[4];
  const float* Wv = (const float*)d_in[5];
  const float* bv = (const float*)d_in[6];
  const float* Wo = (const float*)d_in[7];
  const float* bo = (const float*)d_in[8];
  const float* gamma = (const float*)d_in[9];
  const float* beta = (const float*)d_in[10];

  char* ws = (char*)d_ws;
  size_t off = 0;
  bf16_t* xb = (bf16_t*)(ws + off);  off += (size_t)M_ * D_ * 2;
  bf16_t* Wqb = (bf16_t*)(ws + off); off += (size_t)D_ * D_ * 2;
  bf16_t* Wkb = (bf16_t*)(ws + off); off += (size_t)D_ * D_ * 2;
  bf16_t* Wvb = (bf16_t*)(ws + off); off += (size_t)D_ * D_ * 2;
  bf16_t* Wob = (bf16_t*)(ws + off); off += (size_t)D_ * D_ * 2;
  bf16_t* Qb = (bf16_t*)(ws + off);  off += (size_t)M_ * D_ * 2;
  bf16_t* Kb = (bf16_t*)(ws + off);  off += (size_t)M_ * D_ * 2;
  bf16_t* Vb = (bf16_t*)(ws + off);  off += (size_t)M_ * D_ * 2;
  bf16_t* Vtb = (bf16_t*)(ws + off); off += (size_t)M_ * D_ * 2;
  bf16_t* ctxb = (bf16_t*)(ws + off); off += (size_t)M_ * D_ * 2;

  float* out0 = (float*)d_out;
  float* alpha = out0 + (size_t)M_ * D_;

  cvt_all<<<6144, 256, 0, stream>>>(x, Wq, Wk, Wv, Wo, xb, Wqb, Wkb, Wvb, Wob);

  gemm_qkv8<<<384, 512, 0, stream>>>(xb, Wqb, Wkb, Wvb, bq, bk, bv, Qb, Kb, Vb);
  transpose_v<<<1024, 256, 0, stream>>>(Vb, Vtb);
  attn_kernel<<<4096, 512, 0, stream>>>(Qb, Kb, Vtb, alpha, ctxb);
  gemm_proj<<<dim3(8, 64), 256, 0, stream>>>(ctxb, Wob, bo, x, out0);
  ln_kernel<<<8192, 256, 0, stream>>>(out0, gamma, beta);
}

// Round 8
// 2106.164 us; speedup vs baseline: 1.0171x; 1.0171x over previous
//
#include <hip/hip_runtime.h>
#include <stdint.h>
#include <math.h>

typedef __bf16 bf16_t;
typedef float f32x4 __attribute__((ext_vector_type(4)));
typedef __bf16 bf16x8 __attribute__((ext_vector_type(8)));
typedef __bf16 bf16x4 __attribute__((ext_vector_type(4)));

#define D_ 1024
#define M_ 8192

// ======== DIAGNOSTIC: rep-loops amplify kernels into rocprof top-5 ========
#define REP_ATTN 4
#define REP_QKV 8
#define REP_PROJ 12

__device__ __forceinline__ f32x4 mfma16(bf16x8 a, bf16x8 b, f32x4 c) {
  return __builtin_amdgcn_mfma_f32_16x16x32_bf16(a, b, c, 0, 0, 0);
}

__device__ __forceinline__ void gl_lds16(const bf16_t* g, bf16_t* l) {
  __builtin_amdgcn_global_load_lds(
      (const __attribute__((address_space(1))) unsigned int*)g,
      (__attribute__((address_space(3))) unsigned int*)l, 16, 0, 0);
}

// ---------------- all fp32 -> bf16 converts in ONE launch ----------------
__global__ __launch_bounds__(256) void cvt_all(
    const float* __restrict__ x,
    const float* __restrict__ w0, const float* __restrict__ w1,
    const float* __restrict__ w2, const float* __restrict__ w3,
    bf16_t* __restrict__ xb,
    bf16_t* __restrict__ d0, bf16_t* __restrict__ d1,
    bf16_t* __restrict__ d2, bf16_t* __restrict__ d3) {
  int b = blockIdx.x;
  const float* s;
  bf16_t* d;
  int i;
  if (b < 4096) {
    s = x; d = xb; i = b * 256 + threadIdx.x;
  } else {
    int g = b - 4096;
    int which = g >> 9;
    s = which == 0 ? w0 : which == 1 ? w1 : which == 2 ? w2 : w3;
    d = which == 0 ? d0 : which == 1 ? d1 : which == 2 ? d2 : d3;
    i = (g & 511) * 256 + threadIdx.x;
  }
  const f32x4* p = (const f32x4*)(s + (size_t)i * 8);
  f32x4 a = p[0], bb = p[1];
  bf16x8 o;
  o[0] = (bf16_t)a.x; o[1] = (bf16_t)a.y; o[2] = (bf16_t)a.z; o[3] = (bf16_t)a.w;
  o[4] = (bf16_t)bb.x; o[5] = (bf16_t)bb.y; o[6] = (bf16_t)bb.z; o[7] = (bf16_t)bb.w;
  *(bf16x8*)(d + (size_t)i * 8) = o;
}

// ================= QKV: 256x256 8-phase pipelined GEMM =================
// Full 3-bit slot swizzle: physical_slot = logical_slot ^ (row & 7).
// Write side: linear LDS dest (gl_lds requirement) + inverse-permuted global
// column (scol). Read side: eCol = (lg ^ (lr&7))*8; chunk j=1 via offset^32.
#define LDSB(e) (*(const bf16x8*)(Sm + (e)))

#define STG_AH(b, h, kt)                                                      \
  {                                                                           \
    gl_lds16(A + sA + (h) * 131072 + (kt) * 64,                               \
             Sm + (b) * 32768 + (h) * 8192 + tid * 8);                        \
    gl_lds16(A + sA + (h) * 131072 + 65536 + (kt) * 64,                       \
             Sm + (b) * 32768 + (h) * 8192 + 4096 + tid * 8);                 \
  }
#define STG_BH(b, h, kt)                                                      \
  {                                                                           \
    gl_lds16(Wsel + sB + (h) * 131072 + (kt) * 64,                            \
             Sm + (b) * 32768 + 16384 + (h) * 8192 + tid * 8);                \
    gl_lds16(Wsel + sB + (h) * 131072 + 65536 + (kt) * 64,                    \
             Sm + (b) * 32768 + 16384 + (h) * 8192 + 4096 + tid * 8);         \
  }

#define QUAD(B, S0, S1, S2, S3)                                               \
  {                                                                           \
    const int bb = (B) * 32768;                                               \
    _Pragma("unroll") for (int q = 0; q < 4; ++q) {                           \
      if (q == 0) {                                                           \
        _Pragma("unroll") for (int fn = 0; fn < 4; ++fn) {                    \
          bfr[fn][0] = LDSB(bb + bBase + fn * 1024);                          \
          bfr[fn][1] = LDSB((bb + bBase + fn * 1024) ^ 32);                   \
        }                                                                     \
      }                                                                       \
      bf16x8 af[2][2];                                                        \
      _Pragma("unroll") for (int mi = 0; mi < 2; ++mi) {                      \
        af[mi][0] = LDSB(bb + aBase + (2 * q + mi) * 1024);                   \
        af[mi][1] = LDSB((bb + aBase + (2 * q + mi) * 1024) ^ 32);            \
      }                                                                       \
      if (q == 0) { S0; } else if (q == 1) { S1; }                            \
      else if (q == 2) { S2; } else { S3; }                                   \
      __builtin_amdgcn_s_barrier();                                           \
      __builtin_amdgcn_s_setprio(1);                                          \
      _Pragma("unroll") for (int mi = 0; mi < 2; ++mi)                        \
      _Pragma("unroll") for (int fn = 0; fn < 4; ++fn) {                      \
        acc[2 * q + mi][fn] =                                                 \
            mfma16(af[mi][0], bfr[fn][0], acc[2 * q + mi][fn]);               \
        acc[2 * q + mi][fn] =                                                 \
            mfma16(af[mi][1], bfr[fn][1], acc[2 * q + mi][fn]);               \
      }                                                                       \
      __builtin_amdgcn_s_setprio(0);                                          \
      __builtin_amdgcn_s_barrier();                                           \
    }                                                                         \
  }

__global__ __launch_bounds__(512) void gemm_qkv8(
    const bf16_t* __restrict__ A,
    const bf16_t* __restrict__ Wq, const bf16_t* __restrict__ Wk,
    const bf16_t* __restrict__ Wv,
    const float* __restrict__ bq, const float* __restrict__ bk,
    const float* __restrict__ bv,
    bf16_t* __restrict__ Oq, bf16_t* __restrict__ Ok, bf16_t* __restrict__ Ov) {
  __shared__ bf16_t Sm[65536];  // 128 KiB

  const int tid = threadIdx.x;
  const int l = tid & 63, w = tid >> 6;
  const int wm = w >> 2, wn = w & 3;
  const int lr = l & 15, lg = l >> 4;

  // 2D XCD chunk: each XCD owns 4 consecutive bm x all 12 (N,which) panels.
  int wg = blockIdx.x;
  int xcd = wg & 7, local = wg >> 3;        // local 0..47
  int bm = xcd * 4 + (local & 3);           // 0..31
  int bnid = local >> 2;                    // 0..11
  int which = bnid >> 2;
  const bf16_t* Wsel = which == 0 ? Wq : (which == 1 ? Wk : Wv);
  const float* bias = which == 0 ? bq : (which == 1 ? bk : bv);
  bf16_t* O = which == 0 ? Oq : (which == 1 ? Ok : Ov);
  const float scale = which == 0 ? 0.18033688f : 1.0f;  // 0.125*log2(e) on Q
  const int m0 = bm * 256, n0 = (bnid & 3) * 256;

  // staging: dest (row=tid>>3, slot=tid&7) must hold logical slot
  // (tid&7)^((tid>>3)&7)  ->  pre-swizzled source column
  const int scol = ((l & 7) ^ ((l >> 3) & 7)) * 8;
  const int sA = (m0 + w * 8 + (l >> 3)) * 1024 + scol;
  const int sB = (n0 + w * 8 + (l >> 3)) * 1024 + scol;

  // ds_read: logical slot lg at row lr -> physical slot lg^(lr&7)
  const int eCol = (lg ^ (lr & 7)) * 8;
  const int aBase = wm * 8192 + lr * 64 + eCol;
  const int bBase = 16384 + (wn >> 1) * 8192 + ((wn & 1) * 64 + lr) * 64 + eCol;

  for (int rep = 0; rep < REP_QKV; ++rep) {
    __syncthreads();
    f32x4 acc[8][4] = {};
    bf16x8 bfr[4][2];

    STG_AH(0, 0, 0) STG_AH(0, 1, 0) STG_BH(0, 0, 0) STG_BH(0, 1, 0)
    STG_BH(1, 0, 1) STG_BH(1, 1, 1) STG_AH(1, 0, 1)
    asm volatile("s_waitcnt vmcnt(6)" ::: "memory");
    __builtin_amdgcn_sched_barrier(0);
    __builtin_amdgcn_s_barrier();

    for (int i = 0; i < 8; ++i) {
      const bool st = (i < 7);
      const int k2 = 2 * i + 2, k3 = 2 * i + 3;
      QUAD(0,
           STG_AH(1, 1, 2 * i + 1),
           if (st) STG_BH(0, 0, k2),
           if (st) STG_BH(0, 1, k2),
           if (st) STG_AH(0, 0, k2))
      if (i < 7) {
        asm volatile("s_waitcnt vmcnt(6)" ::: "memory");
      } else {
        asm volatile("s_waitcnt vmcnt(0)" ::: "memory");
      }
      __builtin_amdgcn_sched_barrier(0);
      QUAD(1,
           if (st) STG_AH(0, 1, k2),
           if (st) STG_BH(1, 0, k3),
           if (st) STG_BH(1, 1, k3),
           if (st) STG_AH(1, 0, k3))
      if (i < 7) {
        asm volatile("s_waitcnt vmcnt(6)" ::: "memory");
        __builtin_amdgcn_sched_barrier(0);
      }
    }

#pragma unroll
    for (int fn = 0; fn < 4; ++fn) {
      int col = n0 + wn * 64 + fn * 16 + lr;
      float bb2 = bias[col];
#pragma unroll
      for (int fm = 0; fm < 8; ++fm) {
        int row = m0 + wm * 128 + fm * 16 + lg * 4;
        bf16_t* op = O + (size_t)row * 1024 + col;
#pragma unroll
        for (int r = 0; r < 4; ++r)
          op[(size_t)r * 1024] = (bf16_t)((acc[fm][fn][r] + bb2) * scale);
      }
    }
  }
}

// ---------------- shared 128x128x(K=1024) bf16 GEMM core ----------------
__device__ __forceinline__ void gemm_core(const bf16_t* __restrict__ A,
                                          const bf16_t* __restrict__ W,
                                          int m0, int n0,
                                          bf16_t* As, bf16_t* Bs,
                                          f32x4 acc[4][4]) {
  const int t = threadIdx.x;
  const int l = t & 63, w = t >> 6;
  const int wr = w >> 1, wc = w & 1;
  const int lr = l & 15, lg = l >> 4;
  const int srow = t >> 2;
  const int scol = (t & 3) * 8;
  const bf16_t* gA0 = A + (size_t)(m0 + srow) * D_ + scol;
  const bf16_t* gA1 = A + (size_t)(m0 + 64 + srow) * D_ + scol;
  const bf16_t* gB0 = W + (size_t)(n0 + srow) * D_ + scol;
  const bf16_t* gB1 = W + (size_t)(n0 + 64 + srow) * D_ + scol;

  for (int k0 = 0; k0 < D_; k0 += 32) {
    gl_lds16(gA0 + k0, As + t * 8);
    gl_lds16(gA1 + k0, As + 2048 + t * 8);
    gl_lds16(gB0 + k0, Bs + t * 8);
    gl_lds16(gB1 + k0, Bs + 2048 + t * 8);
    __syncthreads();
    bf16x8 af[4], bfr[4];
#pragma unroll
    for (int i = 0; i < 4; ++i)
      af[i] = *(const bf16x8*)(As + (wr * 64 + i * 16 + lr) * 32 + lg * 8);
#pragma unroll
    for (int i = 0; i < 4; ++i)
      bfr[i] = *(const bf16x8*)(Bs + (wc * 64 + i * 16 + lr) * 32 + lg * 8);
#pragma unroll
    for (int mi = 0; mi < 4; ++mi)
#pragma unroll
      for (int ni = 0; ni < 4; ++ni)
        acc[mi][ni] = mfma16(af[mi], bfr[ni], acc[mi][ni]);
    __syncthreads();
  }
}

// ---------------- proj GEMM: out fp32 = acc + bo + x (residual) ----------------
__global__ __launch_bounds__(256) void gemm_proj(
    const bf16_t* __restrict__ A, const bf16_t* __restrict__ W,
    const float* __restrict__ bias, const float* __restrict__ xres,
    float* __restrict__ O) {
  __shared__ bf16_t As[128 * 32], Bs[128 * 32];
  int m0 = blockIdx.y * 128, n0 = blockIdx.x * 128;
  int t = threadIdx.x, l = t & 63, w = t >> 6;
  int wr = w >> 1, wc = w & 1, lr = l & 15, lg = l >> 4;
  for (int rep = 0; rep < REP_PROJ; ++rep) {
    __syncthreads();
    f32x4 acc[4][4] = {};
    gemm_core(A, W, m0, n0, As, Bs, acc);
#pragma unroll
    for (int mi = 0; mi < 4; ++mi) {
#pragma unroll
      for (int ni = 0; ni < 4; ++ni) {
        int col = n0 + wc * 64 + ni * 16 + lr;
        float bb = bias[col];
        int row = m0 + wr * 64 + mi * 16 + lg * 4;
#pragma unroll
        for (int r = 0; r < 4; ++r) {
          size_t idx = (size_t)(row + r) * D_ + col;
          O[idx] = acc[mi][ni][r] + bb + xres[idx];
        }
      }
    }
  }
}

// ---------------- V transpose via LDS tile ----------------
__global__ __launch_bounds__(256) void transpose_v(const bf16_t* __restrict__ V,
                                                   bf16_t* __restrict__ Vt) {
  __shared__ float sT[128 * 33];
  int bh = blockIdx.x >> 3, st = blockIdx.x & 7;
  int s0 = st * 128;
  int t = threadIdx.x;
  const bf16_t* src = V + (size_t)bh * 65536 + (size_t)s0 * 64;
  int li = t >> 3, lc = t & 7;
#pragma unroll
  for (int p = 0; p < 4; ++p) {
    int row = p * 32 + li;
    f32x4 v = *(const f32x4*)(src + (size_t)row * 64 + lc * 8);
    float* dst = &sT[row * 33 + lc * 4];
    dst[0] = v[0]; dst[1] = v[1]; dst[2] = v[2]; dst[3] = v[3];
  }
  __syncthreads();
  int sc = t & 15, dh0 = t >> 4;
  bf16_t* dstb = Vt + (size_t)bh * 65536;
#pragma unroll
  for (int p = 0; p < 4; ++p) {
    int dh = dh0 + p * 16;
    bf16x8 o;
#pragma unroll
    for (int j = 0; j < 8; ++j) {
      int s = sc * 8 + j;
      o[j] = ((const bf16_t*)&sT[s * 33 + (dh >> 1)])[dh & 1];
    }
    *(bf16x8*)(dstb + (size_t)dh * 1024 + s0 + sc * 8) = o;
  }
}

// ---------------- fused attention per (bh, 32-row q tile) ----------------
#define SP_STRIDE 1064
__global__ __launch_bounds__(512, 4) void attn_kernel(
    const bf16_t* __restrict__ Q, const bf16_t* __restrict__ K,
    const bf16_t* __restrict__ Vt, float* __restrict__ alpha,
    bf16_t* __restrict__ ctx) {
  __shared__ bf16_t sP[32][SP_STRIDE];
  __shared__ float sRS[8][32];
  __shared__ float sL[32];

  int id = blockIdx.x;
  int g = id >> 3, x = id & 7;
  int qt = g & 31;
  int bh = ((g >> 5) << 3) | x;
  int q0 = qt * 32;

  const bf16_t* Qb = Q + (size_t)bh * 65536;
  const bf16_t* Kb = K + (size_t)bh * 65536;
  const bf16_t* Vb = Vt + (size_t)bh * 65536;
  float* Ab = alpha + (size_t)bh * 1048576 + (size_t)q0 * 1024;

  int t = threadIdx.x, l = t & 63, w = t >> 6;
  int lr = l & 15, lg = l >> 4;

  bf16x8 qa[2][2];
#pragma unroll
  for (int mi = 0; mi < 2; ++mi)
#pragma unroll
    for (int kk = 0; kk < 2; ++kk)
      qa[mi][kk] = *(const bf16x8*)(Qb + (size_t)(q0 + mi * 16 + lr) * 64 + kk * 32 + lg * 8);

  for (int rep = 0; rep < REP_ATTN; ++rep) {
    __syncthreads();
    float pa0 = 0.f, pa1 = 0.f;
#pragma unroll
    for (int tt = 0; tt < 8; ++tt) {
      int n0 = w * 128 + tt * 16;
      bf16x8 kb0 = *(const bf16x8*)(Kb + (size_t)(n0 + lr) * 64 + lg * 8);
      bf16x8 kb1 = *(const bf16x8*)(Kb + (size_t)(n0 + lr) * 64 + 32 + lg * 8);
      f32x4 a0 = {0.f, 0.f, 0.f, 0.f};
      f32x4 a1 = {0.f, 0.f, 0.f, 0.f};
      a0 = mfma16(kb0, qa[0][0], a0);
      a0 = mfma16(kb1, qa[0][1], a0);
      a1 = mfma16(kb0, qa[1][0], a1);
      a1 = mfma16(kb1, qa[1][1], a1);
      bf16x4 w0, w1;
#pragma unroll
      for (int r = 0; r < 4; ++r) {
        float e0 = exp2f(a0[r]);
        float e1 = exp2f(a1[r]);
        pa0 += e0; pa1 += e1;
        w0[r] = (bf16_t)e0;
        w1[r] = (bf16_t)e1;
      }
      *(bf16x4*)&sP[lr][n0 + lg * 4] = w0;
      *(bf16x4*)&sP[16 + lr][n0 + lg * 4] = w1;
    }
    pa0 += __shfl_xor(pa0, 16); pa0 += __shfl_xor(pa0, 32);
    pa1 += __shfl_xor(pa1, 16); pa1 += __shfl_xor(pa1, 32);
    if (l < 16) {
      sRS[w][lr] = pa0;
      sRS[w][16 + lr] = pa1;
    }
    __syncthreads();
    if (t < 32) {
      float s = 0.f;
#pragma unroll
      for (int ww = 0; ww < 8; ++ww) s += sRS[ww][t];
      sL[t] = 1.0f / s;
    }
    __syncthreads();

    {
      int wm = w >> 2, wn = w & 3;
      f32x4 acc = {0.f, 0.f, 0.f, 0.f};
      const bf16_t* vp = Vb + (size_t)(wn * 16 + lr) * 1024 + lg * 8;
      const bf16_t* pp = &sP[wm * 16 + lr][lg * 8];
      int arow = t >> 4, acol = (t & 15) * 4;
      float inv = sL[arow];
      const bf16_t* ap = &sP[arow][acol];
      float* aout = Ab + (size_t)arow * 1024 + acol;
#pragma unroll 4
      for (int n0 = 0; n0 < 1024; n0 += 64) {
        bf16x8 ea0 = *(const bf16x8*)(pp + n0);
        bf16x8 vb0 = *(const bf16x8*)(vp + n0);
        acc = mfma16(ea0, vb0, acc);
        bf16x8 ea1 = *(const bf16x8*)(pp + n0 + 32);
        bf16x8 vb1 = *(const bf16x8*)(vp + n0 + 32);
        acc = mfma16(ea1, vb1, acc);
        bf16x4 p = *(const bf16x4*)(ap + n0);
        f32x4 o;
        o[0] = (float)p[0] * inv;
        o[1] = (float)p[1] * inv;
        o[2] = (float)p[2] * inv;
        o[3] = (float)p[3] * inv;
        __builtin_nontemporal_store(o, (f32x4*)(aout + n0));
      }
      bf16_t* cp = ctx + (size_t)bh * 65536 + (size_t)(q0 + wm * 16 + lg * 4) * 64 + wn * 16 + lr;
#pragma unroll
      for (int r = 0; r < 4; ++r)
        cp[(size_t)r * 64] = (bf16_t)(acc[r] * sL[wm * 16 + lg * 4 + r]);
    }
  }
}

// ---------------- LayerNorm in place on d_out rows ----------------
__global__ __launch_bounds__(256) void ln_kernel(float* __restrict__ io,
                                                 const float* __restrict__ gamma,
                                                 const float* __restrict__ beta) {
  int row = blockIdx.x;
  int t = threadIdx.x;
  float* p = io + (size_t)row * 1024;
  f32x4 v = *(const f32x4*)(p + t * 4);
  float s = v[0] + v[1] + v[2] + v[3];
  float s2 = v[0] * v[0] + v[1] * v[1] + v[2] * v[2] + v[3] * v[3];
#pragma unroll
  for (int off = 1; off <= 32; off <<= 1) {
    s += __shfl_xor(s, off);
    s2 += __shfl_xor(s2, off);
  }
  __shared__ float ps[4], ps2[4];
  int w = t >> 6, l = t & 63;
  if (l == 0) { ps[w] = s; ps2[w] = s2; }
  __syncthreads();
  float S = ps[0] + ps[1] + ps[2] + ps[3];
  float S2 = ps2[0] + ps2[1] + ps2[2] + ps2[3];
  float mu = S * (1.f / 1024.f);
  float var = S2 * (1.f / 1024.f) - mu * mu;
  float rs = rsqrtf(var + 1e-5f);
  f32x4 g = *(const f32x4*)(gamma + t * 4);
  f32x4 b = *(const f32x4*)(beta + t * 4);
  f32x4 o;
  o[0] = (v[0] - mu) * rs * g[0] + b[0];
  o[1] = (v[1] - mu) * rs * g[1] + b[1];
  o[2] = (v[2] - mu) * rs * g[2] + b[2];
  o[3] = (v[3] - mu) * rs * g[3] + b[3];
  *(f32x4*)(p + t * 4) = o;
}

extern "C" void kernel_launch(void* const* d_in, const int* in_sizes, int n_in,
                              void* d_out, int out_size, void* d_ws, size_t ws_size,
                              hipStream_t stream) {
  const float* x = (const float*)d_in[0];
  const float* Wq = (const float*)d_in[1];
  const float* bq = (const float*)d_in[2];
  const float* Wk = (const float*)d_in[3];
  const float* bk = (const float*)d_in[4];
  const float* Wv = (const float*)d_in[5];
  const float* bv = (const float*)d_in[6];
  const float* Wo = (const float*)d_in[7];
  const float* bo = (const float*)d_in[8];
  const float* gamma = (const float*)d_in[9];
  const float* beta = (const float*)d_in[10];

  char* ws = (char*)d_ws;
  size_t off = 0;
  bf16_t* xb = (bf16_t*)(ws + off);  off += (size_t)M_ * D_ * 2;
  bf16_t* Wqb = (bf16_t*)(ws + off); off += (size_t)D_ * D_ * 2;
  bf16_t* Wkb = (bf16_t*)(ws + off); off += (size_t)D_ * D_ * 2;
  bf16_t* Wvb = (bf16_t*)(ws + off); off += (size_t)D_ * D_ * 2;
  bf16_t* Wob = (bf16_t*)(ws + off); off += (size_t)D_ * D_ * 2;
  bf16_t* Qb = (bf16_t*)(ws + off);  off += (size_t)M_ * D_ * 2;
  bf16_t* Kb = (bf16_t*)(ws + off);  off += (size_t)M_ * D_ * 2;
  bf16_t* Vb = (bf16_t*)(ws + off);  off += (size_t)M_ * D_ * 2;
  bf16_t* Vtb = (bf16_t*)(ws + off); off += (size_t)M_ * D_ * 2;
  bf16_t* ctxb = (bf16_t*)(ws + off); off += (size_t)M_ * D_ * 2;

  float* out0 = (float*)d_out;
  float* alpha = out0 + (size_t)M_ * D_;

  cvt_all<<<6144, 256, 0, stream>>>(x, Wq, Wk, Wv, Wo, xb, Wqb, Wkb, Wvb, Wob);

  gemm_qkv8<<<384, 512, 0, stream>>>(xb, Wqb, Wkb, Wvb, bq, bk, bv, Qb, Kb, Vb);
  transpose_v<<<1024, 256, 0, stream>>>(Vb, Vtb);
  attn_kernel<<<4096, 512, 0, stream>>>(Qb, Kb, Vtb, alpha, ctxb);
  gemm_proj<<<dim3(8, 64), 256, 0, stream>>>(ctxb, Wob, bo, x, out0);
  ln_kernel<<<8192, 256, 0, stream>>>(out0, gamma, beta);
}

// Round 9
// 330.994 us; speedup vs baseline: 6.4722x; 6.3631x over previous
//
#include <hip/hip_runtime.h>
#include <stdint.h>
#include <math.h>

typedef __bf16 bf16_t;
typedef float f32x4 __attribute__((ext_vector_type(4)));
typedef __bf16 bf16x8 __attribute__((ext_vector_type(8)));
typedef __bf16 bf16x4 __attribute__((ext_vector_type(4)));

#define D_ 1024
#define M_ 8192

__device__ __forceinline__ f32x4 mfma16(bf16x8 a, bf16x8 b, f32x4 c) {
  return __builtin_amdgcn_mfma_f32_16x16x32_bf16(a, b, c, 0, 0, 0);
}

__device__ __forceinline__ void gl_lds16(const bf16_t* g, bf16_t* l) {
  __builtin_amdgcn_global_load_lds(
      (const __attribute__((address_space(1))) unsigned int*)g,
      (__attribute__((address_space(3))) unsigned int*)l, 16, 0, 0);
}

// ---------------- all fp32 -> bf16 converts in ONE launch ----------------
__global__ __launch_bounds__(256) void cvt_all(
    const float* __restrict__ x,
    const float* __restrict__ w0, const float* __restrict__ w1,
    const float* __restrict__ w2, const float* __restrict__ w3,
    bf16_t* __restrict__ xb,
    bf16_t* __restrict__ d0, bf16_t* __restrict__ d1,
    bf16_t* __restrict__ d2, bf16_t* __restrict__ d3) {
  int b = blockIdx.x;
  const float* s;
  bf16_t* d;
  int i;
  if (b < 4096) {
    s = x; d = xb; i = b * 256 + threadIdx.x;
  } else {
    int g = b - 4096;
    int which = g >> 9;
    s = which == 0 ? w0 : which == 1 ? w1 : which == 2 ? w2 : w3;
    d = which == 0 ? d0 : which == 1 ? d1 : which == 2 ? d2 : d3;
    i = (g & 511) * 256 + threadIdx.x;
  }
  const f32x4* p = (const f32x4*)(s + (size_t)i * 8);
  f32x4 a = p[0], bb = p[1];
  bf16x8 o;
  o[0] = (bf16_t)a.x; o[1] = (bf16_t)a.y; o[2] = (bf16_t)a.z; o[3] = (bf16_t)a.w;
  o[4] = (bf16_t)bb.x; o[5] = (bf16_t)bb.y; o[6] = (bf16_t)bb.z; o[7] = (bf16_t)bb.w;
  *(bf16x8*)(d + (size_t)i * 8) = o;
}

// ================= QKV: 256x256 2-phase double-buffered GEMM =================
// One barrier + one vmcnt(0) per K-tile (16 total). Zero-conflict XOR slot
// swizzle (verified R8): LDS phys slot = logical slot ^ (row&7); linear DMA
// dest + inverse-permuted global source; reads use (lg^(lr&7))*8, chunk1 ^32.
#define LDSB(e) (*(const bf16x8*)(Sm + (e)))

#define STG2(b, kt)                                                          \
  {                                                                          \
    _Pragma("unroll") for (int c = 0; c < 4; ++c) {                          \
      gl_lds16(A + (size_t)(m0 + c * 64 + srow) * 1024 + (kt) * 64 + scol,   \
               Sm + (b) * 32768 + c * 4096 + tid * 8);                       \
      gl_lds16(Wsel + (size_t)(n0 + c * 64 + srow) * 1024 + (kt) * 64 + scol,\
               Sm + (b) * 32768 + 16384 + c * 4096 + tid * 8);               \
    }                                                                        \
  }

__global__ __launch_bounds__(512) void gemm_qkv2(
    const bf16_t* __restrict__ A,
    const bf16_t* __restrict__ Wq, const bf16_t* __restrict__ Wk,
    const bf16_t* __restrict__ Wv,
    const float* __restrict__ bq, const float* __restrict__ bk,
    const float* __restrict__ bv,
    bf16_t* __restrict__ Oq, bf16_t* __restrict__ Ok, bf16_t* __restrict__ Ov) {
  __shared__ bf16_t Sm[65536];  // 128 KiB: 2 bufs x (A 16K elems + B 16K)

  const int tid = threadIdx.x;
  const int l = tid & 63, w = tid >> 6;
  const int wm = w >> 2, wn = w & 3;
  const int lr = l & 15, lg = l >> 4;

  // 2D XCD chunk: each XCD owns 4 consecutive bm x all 12 (N,which) panels.
  int wg = blockIdx.x;
  int xcd = wg & 7, local = wg >> 3;
  int bm = xcd * 4 + (local & 3);
  int bnid = local >> 2;
  int which = bnid >> 2;
  const bf16_t* Wsel = which == 0 ? Wq : (which == 1 ? Wk : Wv);
  const float* bias = which == 0 ? bq : (which == 1 ? bk : bv);
  bf16_t* O = which == 0 ? Oq : (which == 1 ? Ok : Ov);
  const float scale = which == 0 ? 0.18033688f : 1.0f;  // 0.125*log2(e) on Q
  const int m0 = bm * 256, n0 = (bnid & 3) * 256;

  // staging source pre-swizzle (bijective per 8-row stripe)
  const int scol = ((l & 7) ^ ((l >> 3) & 7)) * 8;
  const int srow = w * 8 + (l >> 3);  // 0..63

  // ds_read bases: logical slot lg at row -> phys slot lg^(row&7)
  const int rdA = (wm * 128 + lr) * 64 + (lg ^ (lr & 7)) * 8;
  const int rdB = 16384 + (wn * 64 + lr) * 64 + (lg ^ (lr & 7)) * 8;

  f32x4 acc[8][4] = {};

  STG2(0, 0)
  asm volatile("s_waitcnt vmcnt(0)" ::: "memory");
  __builtin_amdgcn_sched_barrier(0);
  __builtin_amdgcn_s_barrier();

  int cur = 0;
  for (int kt = 0; kt < 16; ++kt) {
    if (kt < 15) STG2(cur ^ 1, kt + 1)
    const int bb = cur * 32768;
    bf16x8 bfr[4][2];
#pragma unroll
    for (int fn = 0; fn < 4; ++fn) {
      bfr[fn][0] = LDSB(bb + rdB + fn * 1024);
      bfr[fn][1] = LDSB((bb + rdB + fn * 1024) ^ 32);
    }
#pragma unroll
    for (int fm = 0; fm < 8; ++fm) {
      bf16x8 a0 = LDSB(bb + rdA + fm * 1024);
      bf16x8 a1 = LDSB((bb + rdA + fm * 1024) ^ 32);
#pragma unroll
      for (int fn = 0; fn < 4; ++fn) {
        acc[fm][fn] = mfma16(a0, bfr[fn][0], acc[fm][fn]);
        acc[fm][fn] = mfma16(a1, bfr[fn][1], acc[fm][fn]);
      }
    }
    asm volatile("s_waitcnt vmcnt(0)" ::: "memory");
    __builtin_amdgcn_sched_barrier(0);
    __builtin_amdgcn_s_barrier();
    cur ^= 1;
  }

  // ---- epilogue ----
#pragma unroll
  for (int fn = 0; fn < 4; ++fn) {
    int col = n0 + wn * 64 + fn * 16 + lr;
    float bb2 = bias[col];
#pragma unroll
    for (int fm = 0; fm < 8; ++fm) {
      int row = m0 + wm * 128 + fm * 16 + lg * 4;
      bf16_t* op = O + (size_t)row * 1024 + col;
#pragma unroll
      for (int r = 0; r < 4; ++r)
        op[(size_t)r * 1024] = (bf16_t)((acc[fm][fn][r] + bb2) * scale);
    }
  }
}

// ---------------- shared 128x128x(K=1024) bf16 GEMM core ----------------
__device__ __forceinline__ void gemm_core(const bf16_t* __restrict__ A,
                                          const bf16_t* __restrict__ W,
                                          int m0, int n0,
                                          bf16_t* As, bf16_t* Bs,
                                          f32x4 acc[4][4]) {
  const int t = threadIdx.x;
  const int l = t & 63, w = t >> 6;
  const int wr = w >> 1, wc = w & 1;
  const int lr = l & 15, lg = l >> 4;
  const int srow = t >> 2;
  const int scol = (t & 3) * 8;
  const bf16_t* gA0 = A + (size_t)(m0 + srow) * D_ + scol;
  const bf16_t* gA1 = A + (size_t)(m0 + 64 + srow) * D_ + scol;
  const bf16_t* gB0 = W + (size_t)(n0 + srow) * D_ + scol;
  const bf16_t* gB1 = W + (size_t)(n0 + 64 + srow) * D_ + scol;

  for (int k0 = 0; k0 < D_; k0 += 32) {
    gl_lds16(gA0 + k0, As + t * 8);
    gl_lds16(gA1 + k0, As + 2048 + t * 8);
    gl_lds16(gB0 + k0, Bs + t * 8);
    gl_lds16(gB1 + k0, Bs + 2048 + t * 8);
    __syncthreads();
    bf16x8 af[4], bfr[4];
#pragma unroll
    for (int i = 0; i < 4; ++i)
      af[i] = *(const bf16x8*)(As + (wr * 64 + i * 16 + lr) * 32 + lg * 8);
#pragma unroll
    for (int i = 0; i < 4; ++i)
      bfr[i] = *(const bf16x8*)(Bs + (wc * 64 + i * 16 + lr) * 32 + lg * 8);
#pragma unroll
    for (int mi = 0; mi < 4; ++mi)
#pragma unroll
      for (int ni = 0; ni < 4; ++ni)
        acc[mi][ni] = mfma16(af[mi], bfr[ni], acc[mi][ni]);
    __syncthreads();
  }
}

// ---------------- proj GEMM: out fp32 = acc + bo + x (residual) ----------------
__global__ __launch_bounds__(256) void gemm_proj(
    const bf16_t* __restrict__ A, const bf16_t* __restrict__ W,
    const float* __restrict__ bias, const float* __restrict__ xres,
    float* __restrict__ O) {
  __shared__ bf16_t As[128 * 32], Bs[128 * 32];
  int m0 = blockIdx.y * 128, n0 = blockIdx.x * 128;
  f32x4 acc[4][4] = {};
  gemm_core(A, W, m0, n0, As, Bs, acc);
  int t = threadIdx.x, l = t & 63, w = t >> 6;
  int wr = w >> 1, wc = w & 1, lr = l & 15, lg = l >> 4;
#pragma unroll
  for (int mi = 0; mi < 4; ++mi) {
#pragma unroll
    for (int ni = 0; ni < 4; ++ni) {
      int col = n0 + wc * 64 + ni * 16 + lr;
      float bb = bias[col];
      int row = m0 + wr * 64 + mi * 16 + lg * 4;
#pragma unroll
      for (int r = 0; r < 4; ++r) {
        size_t idx = (size_t)(row + r) * D_ + col;
        O[idx] = acc[mi][ni][r] + bb + xres[idx];
      }
    }
  }
}

// ---------------- V transpose via LDS tile ----------------
__global__ __launch_bounds__(256) void transpose_v(const bf16_t* __restrict__ V,
                                                   bf16_t* __restrict__ Vt) {
  __shared__ float sT[128 * 33];
  int bh = blockIdx.x >> 3, st = blockIdx.x & 7;
  int s0 = st * 128;
  int t = threadIdx.x;
  const bf16_t* src = V + (size_t)bh * 65536 + (size_t)s0 * 64;
  int li = t >> 3, lc = t & 7;
#pragma unroll
  for (int p = 0; p < 4; ++p) {
    int row = p * 32 + li;
    f32x4 v = *(const f32x4*)(src + (size_t)row * 64 + lc * 8);
    float* dst = &sT[row * 33 + lc * 4];
    dst[0] = v[0]; dst[1] = v[1]; dst[2] = v[2]; dst[3] = v[3];
  }
  __syncthreads();
  int sc = t & 15, dh0 = t >> 4;
  bf16_t* dstb = Vt + (size_t)bh * 65536;
#pragma unroll
  for (int p = 0; p < 4; ++p) {
    int dh = dh0 + p * 16;
    bf16x8 o;
#pragma unroll
    for (int j = 0; j < 8; ++j) {
      int s = sc * 8 + j;
      o[j] = ((const bf16_t*)&sT[s * 33 + (dh >> 1)])[dh & 1];
    }
    *(bf16x8*)(dstb + (size_t)dh * 1024 + s0 + sc * 8) = o;
  }
}

// ---------------- fused attention per (bh, 32-row q tile) ----------------
#define SP_STRIDE 1064
__global__ __launch_bounds__(512, 4) void attn_kernel(
    const bf16_t* __restrict__ Q, const bf16_t* __restrict__ K,
    const bf16_t* __restrict__ Vt, float* __restrict__ alpha,
    bf16_t* __restrict__ ctx) {
  __shared__ bf16_t sP[32][SP_STRIDE];
  __shared__ float sRS[8][32];
  __shared__ float sL[32];

  int id = blockIdx.x;
  int g = id >> 3, x = id & 7;
  int qt = g & 31;
  int bh = ((g >> 5) << 3) | x;
  int q0 = qt * 32;

  const bf16_t* Qb = Q + (size_t)bh * 65536;
  const bf16_t* Kb = K + (size_t)bh * 65536;
  const bf16_t* Vb = Vt + (size_t)bh * 65536;
  float* Ab = alpha + (size_t)bh * 1048576 + (size_t)q0 * 1024;

  int t = threadIdx.x, l = t & 63, w = t >> 6;
  int lr = l & 15, lg = l >> 4;

  bf16x8 qa[2][2];
#pragma unroll
  for (int mi = 0; mi < 2; ++mi)
#pragma unroll
    for (int kk = 0; kk < 2; ++kk)
      qa[mi][kk] = *(const bf16x8*)(Qb + (size_t)(q0 + mi * 16 + lr) * 64 + kk * 32 + lg * 8);

  float pa0 = 0.f, pa1 = 0.f;
#pragma unroll
  for (int tt = 0; tt < 8; ++tt) {
    int n0 = w * 128 + tt * 16;
    bf16x8 kb0 = *(const bf16x8*)(Kb + (size_t)(n0 + lr) * 64 + lg * 8);
    bf16x8 kb1 = *(const bf16x8*)(Kb + (size_t)(n0 + lr) * 64 + 32 + lg * 8);
    f32x4 a0 = {0.f, 0.f, 0.f, 0.f};
    f32x4 a1 = {0.f, 0.f, 0.f, 0.f};
    a0 = mfma16(kb0, qa[0][0], a0);
    a0 = mfma16(kb1, qa[0][1], a0);
    a1 = mfma16(kb0, qa[1][0], a1);
    a1 = mfma16(kb1, qa[1][1], a1);
    bf16x4 w0, w1;
#pragma unroll
    for (int r = 0; r < 4; ++r) {
      float e0 = exp2f(a0[r]);
      float e1 = exp2f(a1[r]);
      pa0 += e0; pa1 += e1;
      w0[r] = (bf16_t)e0;
      w1[r] = (bf16_t)e1;
    }
    *(bf16x4*)&sP[lr][n0 + lg * 4] = w0;
    *(bf16x4*)&sP[16 + lr][n0 + lg * 4] = w1;
  }
  pa0 += __shfl_xor(pa0, 16); pa0 += __shfl_xor(pa0, 32);
  pa1 += __shfl_xor(pa1, 16); pa1 += __shfl_xor(pa1, 32);
  if (l < 16) {
    sRS[w][lr] = pa0;
    sRS[w][16 + lr] = pa1;
  }
  __syncthreads();
  if (t < 32) {
    float s = 0.f;
#pragma unroll
    for (int ww = 0; ww < 8; ++ww) s += sRS[ww][t];
    sL[t] = 1.0f / s;
  }
  __syncthreads();

  {
    int wm = w >> 2, wn = w & 3;
    f32x4 acc = {0.f, 0.f, 0.f, 0.f};
    const bf16_t* vp = Vb + (size_t)(wn * 16 + lr) * 1024 + lg * 8;
    const bf16_t* pp = &sP[wm * 16 + lr][lg * 8];
    int arow = t >> 4, acol = (t & 15) * 4;
    float inv = sL[arow];
    const bf16_t* ap = &sP[arow][acol];
    float* aout = Ab + (size_t)arow * 1024 + acol;
#pragma unroll 4
    for (int n0 = 0; n0 < 1024; n0 += 64) {
      bf16x8 ea0 = *(const bf16x8*)(pp + n0);
      bf16x8 vb0 = *(const bf16x8*)(vp + n0);
      acc = mfma16(ea0, vb0, acc);
      bf16x8 ea1 = *(const bf16x8*)(pp + n0 + 32);
      bf16x8 vb1 = *(const bf16x8*)(vp + n0 + 32);
      acc = mfma16(ea1, vb1, acc);
      bf16x4 p = *(const bf16x4*)(ap + n0);
      f32x4 o;
      o[0] = (float)p[0] * inv;
      o[1] = (float)p[1] * inv;
      o[2] = (float)p[2] * inv;
      o[3] = (float)p[3] * inv;
      __builtin_nontemporal_store(o, (f32x4*)(aout + n0));
    }
    bf16_t* cp = ctx + (size_t)bh * 65536 + (size_t)(q0 + wm * 16 + lg * 4) * 64 + wn * 16 + lr;
#pragma unroll
    for (int r = 0; r < 4; ++r)
      cp[(size_t)r * 64] = (bf16_t)(acc[r] * sL[wm * 16 + lg * 4 + r]);
  }
}

// ---------------- LayerNorm in place on d_out rows ----------------
__global__ __launch_bounds__(256) void ln_kernel(float* __restrict__ io,
                                                 const float* __restrict__ gamma,
                                                 const float* __restrict__ beta) {
  int row = blockIdx.x;
  int t = threadIdx.x;
  float* p = io + (size_t)row * 1024;
  f32x4 v = *(const f32x4*)(p + t * 4);
  float s = v[0] + v[1] + v[2] + v[3];
  float s2 = v[0] * v[0] + v[1] * v[1] + v[2] * v[2] + v[3] * v[3];
#pragma unroll
  for (int off = 1; off <= 32; off <<= 1) {
    s += __shfl_xor(s, off);
    s2 += __shfl_xor(s2, off);
  }
  __shared__ float ps[4], ps2[4];
  int w = t >> 6, l = t & 63;
  if (l == 0) { ps[w] = s; ps2[w] = s2; }
  __syncthreads();
  float S = ps[0] + ps[1] + ps[2] + ps[3];
  float S2 = ps2[0] + ps2[1] + ps2[2] + ps2[3];
  float mu = S * (1.f / 1024.f);
  float var = S2 * (1.f / 1024.f) - mu * mu;
  float rs = rsqrtf(var + 1e-5f);
  f32x4 g = *(const f32x4*)(gamma + t * 4);
  f32x4 b = *(const f32x4*)(beta + t * 4);
  f32x4 o;
  o[0] = (v[0] - mu) * rs * g[0] + b[0];
  o[1] = (v[1] - mu) * rs * g[1] + b[1];
  o[2] = (v[2] - mu) * rs * g[2] + b[2];
  o[3] = (v[3] - mu) * rs * g[3] + b[3];
  *(f32x4*)(p + t * 4) = o;
}

extern "C" void kernel_launch(void* const* d_in, const int* in_sizes, int n_in,
                              void* d_out, int out_size, void* d_ws, size_t ws_size,
                              hipStream_t stream) {
  const float* x = (const float*)d_in[0];
  const float* Wq = (const float*)d_in[1];
  const float* bq = (const float*)d_in[2];
  const float* Wk = (const float*)d_in[3];
  const float* bk = (const float*)d_in[4];
  const float* Wv = (const float*)d_in[5];
  const float* bv = (const float*)d_in[6];
  const float* Wo = (const float*)d_in[7];
  const float* bo = (const float*)d_in[8];
  const float* gamma = (const float*)d_in[9];
  const float* beta = (const float*)d_in[10];

  char* ws = (char*)d_ws;
  size_t off = 0;
  bf16_t* xb = (bf16_t*)(ws + off);  off += (size_t)M_ * D_ * 2;
  bf16_t* Wqb = (bf16_t*)(ws + off); off += (size_t)D_ * D_ * 2;
  bf16_t* Wkb = (bf16_t*)(ws + off); off += (size_t)D_ * D_ * 2;
  bf16_t* Wvb = (bf16_t*)(ws + off); off += (size_t)D_ * D_ * 2;
  bf16_t* Wob = (bf16_t*)(ws + off); off += (size_t)D_ * D_ * 2;
  bf16_t* Qb = (bf16_t*)(ws + off);  off += (size_t)M_ * D_ * 2;
  bf16_t* Kb = (bf16_t*)(ws + off);  off += (size_t)M_ * D_ * 2;
  bf16_t* Vb = (bf16_t*)(ws + off);  off += (size_t)M_ * D_ * 2;
  bf16_t* Vtb = (bf16_t*)(ws + off); off += (size_t)M_ * D_ * 2;
  bf16_t* ctxb = (bf16_t*)(ws + off); off += (size_t)M_ * D_ * 2;

  float* out0 = (float*)d_out;
  float* alpha = out0 + (size_t)M_ * D_;

  cvt_all<<<6144, 256, 0, stream>>>(x, Wq, Wk, Wv, Wo, xb, Wqb, Wkb, Wvb, Wob);

  gemm_qkv2<<<384, 512, 0, stream>>>(xb, Wqb, Wkb, Wvb, bq, bk, bv, Qb, Kb, Vb);
  transpose_v<<<1024, 256, 0, stream>>>(Vb, Vtb);
  attn_kernel<<<4096, 512, 0, stream>>>(Qb, Kb, Vtb, alpha, ctxb);
  gemm_proj<<<dim3(8, 64), 256, 0, stream>>>(ctxb, Wob, bo, x, out0);
  ln_kernel<<<8192, 256, 0, stream>>>(out0, gamma, beta);
}

// Round 10
// 318.873 us; speedup vs baseline: 6.7183x; 1.0380x over previous
//
#include <hip/hip_runtime.h>
#include <stdint.h>
#include <math.h>

typedef __bf16 bf16_t;
typedef float f32x4 __attribute__((ext_vector_type(4)));
typedef __bf16 bf16x8 __attribute__((ext_vector_type(8)));
typedef __bf16 bf16x4 __attribute__((ext_vector_type(4)));

#define D_ 1024
#define M_ 8192

__device__ __forceinline__ f32x4 mfma16(bf16x8 a, bf16x8 b, f32x4 c) {
  return __builtin_amdgcn_mfma_f32_16x16x32_bf16(a, b, c, 0, 0, 0);
}

__device__ __forceinline__ void gl_lds16(const bf16_t* g, bf16_t* l) {
  __builtin_amdgcn_global_load_lds(
      (const __attribute__((address_space(1))) unsigned int*)g,
      (__attribute__((address_space(3))) unsigned int*)l, 16, 0, 0);
}

// ---------------- all fp32 -> bf16 converts in ONE launch ----------------
__global__ __launch_bounds__(256) void cvt_all(
    const float* __restrict__ x,
    const float* __restrict__ w0, const float* __restrict__ w1,
    const float* __restrict__ w2, const float* __restrict__ w3,
    bf16_t* __restrict__ xb,
    bf16_t* __restrict__ d0, bf16_t* __restrict__ d1,
    bf16_t* __restrict__ d2, bf16_t* __restrict__ d3) {
  int b = blockIdx.x;
  const float* s;
  bf16_t* d;
  int i;
  if (b < 4096) {
    s = x; d = xb; i = b * 256 + threadIdx.x;
  } else {
    int g = b - 4096;
    int which = g >> 9;
    s = which == 0 ? w0 : which == 1 ? w1 : which == 2 ? w2 : w3;
    d = which == 0 ? d0 : which == 1 ? d1 : which == 2 ? d2 : d3;
    i = (g & 511) * 256 + threadIdx.x;
  }
  const f32x4* p = (const f32x4*)(s + (size_t)i * 8);
  f32x4 a = p[0], bb = p[1];
  bf16x8 o;
  o[0] = (bf16_t)a.x; o[1] = (bf16_t)a.y; o[2] = (bf16_t)a.z; o[3] = (bf16_t)a.w;
  o[4] = (bf16_t)bb.x; o[5] = (bf16_t)bb.y; o[6] = (bf16_t)bb.z; o[7] = (bf16_t)bb.w;
  *(bf16x8*)(d + (size_t)i * 8) = o;
}

// ============ shared 2-phase 128x256xBK64 double-buffered core =============
// LDS/buf: A[128][64] (8192 el) + B[256][64] (16384 el) = 48 KiB; dbuf 96 KiB.
// Zero-conflict XOR slot swizzle (verified R8): phys slot = logical ^ (row&7);
// linear DMA dest + inverse-permuted global source; reads (lg^(lr&7))*8, ^32.
#define LDSB(e) (*(const bf16x8*)(Sm + (e)))

#define STG26(b, kt)                                                          \
  {                                                                           \
    _Pragma("unroll") for (int c = 0; c < 2; ++c)                             \
        gl_lds16(Ap + (size_t)(m0 + c * 64 + srow) * 1024 + (kt) * 64 + scol, \
                 Sm + (b) * 24576 + c * 4096 + tid * 8);                      \
    _Pragma("unroll") for (int c = 0; c < 4; ++c)                             \
        gl_lds16(Bp + (size_t)(n0 + c * 64 + srow) * 1024 + (kt) * 64 + scol, \
                 Sm + (b) * 24576 + 8192 + c * 4096 + tid * 8);               \
  }

__device__ __forceinline__ void core_128x256(const bf16_t* __restrict__ Ap,
                                             const bf16_t* __restrict__ Bp,
                                             int m0, int n0, bf16_t* Sm,
                                             f32x4 acc[4][4]) {
  const int tid = threadIdx.x;
  const int l = tid & 63, w = tid >> 6;
  const int wm = w >> 2, wn = w & 3;
  const int lr = l & 15, lg = l >> 4;
  const int scol = ((l & 7) ^ ((l >> 3) & 7)) * 8;
  const int srow = tid >> 3;  // 0..63
  const int rdA = (wm * 64 + lr) * 64 + (lg ^ (lr & 7)) * 8;
  const int rdB = 8192 + (wn * 64 + lr) * 64 + (lg ^ (lr & 7)) * 8;

  STG26(0, 0)
  asm volatile("s_waitcnt vmcnt(0)" ::: "memory");
  __builtin_amdgcn_sched_barrier(0);
  __builtin_amdgcn_s_barrier();

  int cur = 0;
  for (int kt = 0; kt < 16; ++kt) {
    if (kt < 15) STG26(cur ^ 1, kt + 1)
    const int bb = cur * 24576;
    bf16x8 bfr[4][2];
#pragma unroll
    for (int fn = 0; fn < 4; ++fn) {
      bfr[fn][0] = LDSB(bb + rdB + fn * 1024);
      bfr[fn][1] = LDSB((bb + rdB + fn * 1024) ^ 32);
    }
#pragma unroll
    for (int fm = 0; fm < 4; ++fm) {
      bf16x8 a0 = LDSB(bb + rdA + fm * 1024);
      bf16x8 a1 = LDSB((bb + rdA + fm * 1024) ^ 32);
#pragma unroll
      for (int fn = 0; fn < 4; ++fn) {
        acc[fm][fn] = mfma16(a0, bfr[fn][0], acc[fm][fn]);
        acc[fm][fn] = mfma16(a1, bfr[fn][1], acc[fm][fn]);
      }
    }
    asm volatile("s_waitcnt vmcnt(0)" ::: "memory");
    __builtin_amdgcn_sched_barrier(0);
    __builtin_amdgcn_s_barrier();
    cur ^= 1;
  }
}

// ---------------- QKV: 768 blocks = 3.0 perfect dispatch waves ----------------
__global__ __launch_bounds__(512) void gemm_qkv2(
    const bf16_t* __restrict__ A,
    const bf16_t* __restrict__ Wq, const bf16_t* __restrict__ Wk,
    const bf16_t* __restrict__ Wv,
    const float* __restrict__ bq, const float* __restrict__ bk,
    const float* __restrict__ bv,
    bf16_t* __restrict__ Oq, bf16_t* __restrict__ Ok, bf16_t* __restrict__ Ov) {
  __shared__ bf16_t Sm[49152];  // 96 KiB

  // XCD chunk: each XCD owns 8 contiguous M-panels x all 12 (N,which) panels
  int wg = blockIdx.x;
  int xcd = wg & 7, local = wg >> 3;          // local 0..95
  int bm = xcd * 8 + (local & 7);             // 0..63
  int bnid = local >> 3;                      // 0..11
  int which = bnid >> 2;
  const bf16_t* Wsel = which == 0 ? Wq : (which == 1 ? Wk : Wv);
  const float* bias = which == 0 ? bq : (which == 1 ? bk : bv);
  bf16_t* O = which == 0 ? Oq : (which == 1 ? Ok : Ov);
  const float scale = which == 0 ? 0.18033688f : 1.0f;  // 0.125*log2(e) on Q
  const int m0 = bm * 128, n0 = (bnid & 3) * 256;

  f32x4 acc[4][4] = {};
  core_128x256(A, Wsel, m0, n0, Sm, acc);

  const int tid = threadIdx.x;
  const int l = tid & 63, w = tid >> 6;
  const int wm = w >> 2, wn = w & 3;
  const int lr = l & 15, lg = l >> 4;
#pragma unroll
  for (int fn = 0; fn < 4; ++fn) {
    int col = n0 + wn * 64 + fn * 16 + lr;
    float bb2 = bias[col];
#pragma unroll
    for (int fm = 0; fm < 4; ++fm) {
      int row = m0 + wm * 64 + fm * 16 + lg * 4;
      bf16_t* op = O + (size_t)row * 1024 + col;
#pragma unroll
      for (int r = 0; r < 4; ++r)
        op[(size_t)r * 1024] = (bf16_t)((acc[fm][fn][r] + bb2) * scale);
    }
  }
}

// ---------------- proj: 256 blocks = 1.0 wave; fp32 + bias + residual ----------------
__global__ __launch_bounds__(512) void gemm_proj2(
    const bf16_t* __restrict__ A, const bf16_t* __restrict__ W,
    const float* __restrict__ bias, const float* __restrict__ xres,
    float* __restrict__ Out) {
  __shared__ bf16_t Sm[49152];

  int wg = blockIdx.x;
  int xcd = wg & 7, local = wg >> 3;          // 0..31
  int bm = xcd * 8 + (local & 7);             // 0..63
  int bn = local >> 3;                        // 0..3
  const int m0 = bm * 128, n0 = bn * 256;

  f32x4 acc[4][4] = {};
  core_128x256(A, W, m0, n0, Sm, acc);

  const int tid = threadIdx.x;
  const int l = tid & 63, w = tid >> 6;
  const int wm = w >> 2, wn = w & 3;
  const int lr = l & 15, lg = l >> 4;
#pragma unroll
  for (int fn = 0; fn < 4; ++fn) {
    int col = n0 + wn * 64 + fn * 16 + lr;
    float bb2 = bias[col];
#pragma unroll
    for (int fm = 0; fm < 4; ++fm) {
      int row = m0 + wm * 64 + fm * 16 + lg * 4;
#pragma unroll
      for (int r = 0; r < 4; ++r) {
        size_t idx = (size_t)(row + r) * 1024 + col;
        Out[idx] = acc[fm][fn][r] + bb2 + xres[idx];
      }
    }
  }
}

// ---------------- V transpose via LDS tile ----------------
__global__ __launch_bounds__(256) void transpose_v(const bf16_t* __restrict__ V,
                                                   bf16_t* __restrict__ Vt) {
  __shared__ float sT[128 * 33];
  int bh = blockIdx.x >> 3, st = blockIdx.x & 7;
  int s0 = st * 128;
  int t = threadIdx.x;
  const bf16_t* src = V + (size_t)bh * 65536 + (size_t)s0 * 64;
  int li = t >> 3, lc = t & 7;
#pragma unroll
  for (int p = 0; p < 4; ++p) {
    int row = p * 32 + li;
    f32x4 v = *(const f32x4*)(src + (size_t)row * 64 + lc * 8);
    float* dst = &sT[row * 33 + lc * 4];
    dst[0] = v[0]; dst[1] = v[1]; dst[2] = v[2]; dst[3] = v[3];
  }
  __syncthreads();
  int sc = t & 15, dh0 = t >> 4;
  bf16_t* dstb = Vt + (size_t)bh * 65536;
#pragma unroll
  for (int p = 0; p < 4; ++p) {
    int dh = dh0 + p * 16;
    bf16x8 o;
#pragma unroll
    for (int j = 0; j < 8; ++j) {
      int s = sc * 8 + j;
      o[j] = ((const bf16_t*)&sT[s * 33 + (dh >> 1)])[dh & 1];
    }
    *(bf16x8*)(dstb + (size_t)dh * 1024 + s0 + sc * 8) = o;
  }
}

// ---------------- fused attention per (bh, 32-row q tile) ----------------
#define SP_STRIDE 1064
__global__ __launch_bounds__(512, 4) void attn_kernel(
    const bf16_t* __restrict__ Q, const bf16_t* __restrict__ K,
    const bf16_t* __restrict__ Vt, float* __restrict__ alpha,
    bf16_t* __restrict__ ctx) {
  __shared__ bf16_t sP[32][SP_STRIDE];
  __shared__ float sRS[8][32];
  __shared__ float sL[32];

  int id = blockIdx.x;
  int g = id >> 3, x = id & 7;
  int qt = g & 31;
  int bh = ((g >> 5) << 3) | x;
  int q0 = qt * 32;

  const bf16_t* Qb = Q + (size_t)bh * 65536;
  const bf16_t* Kb = K + (size_t)bh * 65536;
  const bf16_t* Vb = Vt + (size_t)bh * 65536;
  float* Ab = alpha + (size_t)bh * 1048576 + (size_t)q0 * 1024;

  int t = threadIdx.x, l = t & 63, w = t >> 6;
  int lr = l & 15, lg = l >> 4;

  bf16x8 qa[2][2];
#pragma unroll
  for (int mi = 0; mi < 2; ++mi)
#pragma unroll
    for (int kk = 0; kk < 2; ++kk)
      qa[mi][kk] = *(const bf16x8*)(Qb + (size_t)(q0 + mi * 16 + lr) * 64 + kk * 32 + lg * 8);

  float pa0 = 0.f, pa1 = 0.f;
#pragma unroll
  for (int tt = 0; tt < 8; ++tt) {
    int n0 = w * 128 + tt * 16;
    bf16x8 kb0 = *(const bf16x8*)(Kb + (size_t)(n0 + lr) * 64 + lg * 8);
    bf16x8 kb1 = *(const bf16x8*)(Kb + (size_t)(n0 + lr) * 64 + 32 + lg * 8);
    f32x4 a0 = {0.f, 0.f, 0.f, 0.f};
    f32x4 a1 = {0.f, 0.f, 0.f, 0.f};
    a0 = mfma16(kb0, qa[0][0], a0);
    a0 = mfma16(kb1, qa[0][1], a0);
    a1 = mfma16(kb0, qa[1][0], a1);
    a1 = mfma16(kb1, qa[1][1], a1);
    bf16x4 w0, w1;
#pragma unroll
    for (int r = 0; r < 4; ++r) {
      float e0 = exp2f(a0[r]);
      float e1 = exp2f(a1[r]);
      pa0 += e0; pa1 += e1;
      w0[r] = (bf16_t)e0;
      w1[r] = (bf16_t)e1;
    }
    *(bf16x4*)&sP[lr][n0 + lg * 4] = w0;
    *(bf16x4*)&sP[16 + lr][n0 + lg * 4] = w1;
  }
  pa0 += __shfl_xor(pa0, 16); pa0 += __shfl_xor(pa0, 32);
  pa1 += __shfl_xor(pa1, 16); pa1 += __shfl_xor(pa1, 32);
  if (l < 16) {
    sRS[w][lr] = pa0;
    sRS[w][16 + lr] = pa1;
  }
  __syncthreads();
  if (t < 32) {
    float s = 0.f;
#pragma unroll
    for (int ww = 0; ww < 8; ++ww) s += sRS[ww][t];
    sL[t] = 1.0f / s;
  }
  __syncthreads();

  {
    int wm = w >> 2, wn = w & 3;
    f32x4 acc = {0.f, 0.f, 0.f, 0.f};
    const bf16_t* vp = Vb + (size_t)(wn * 16 + lr) * 1024 + lg * 8;
    const bf16_t* pp = &sP[wm * 16 + lr][lg * 8];
    int arow = t >> 4, acol = (t & 15) * 4;
    float inv = sL[arow];
    const bf16_t* ap = &sP[arow][acol];
    float* aout = Ab + (size_t)arow * 1024 + acol;
#pragma unroll 4
    for (int n0 = 0; n0 < 1024; n0 += 64) {
      bf16x8 ea0 = *(const bf16x8*)(pp + n0);
      bf16x8 vb0 = *(const bf16x8*)(vp + n0);
      acc = mfma16(ea0, vb0, acc);
      bf16x8 ea1 = *(const bf16x8*)(pp + n0 + 32);
      bf16x8 vb1 = *(const bf16x8*)(vp + n0 + 32);
      acc = mfma16(ea1, vb1, acc);
      bf16x4 p = *(const bf16x4*)(ap + n0);
      f32x4 o;
      o[0] = (float)p[0] * inv;
      o[1] = (float)p[1] * inv;
      o[2] = (float)p[2] * inv;
      o[3] = (float)p[3] * inv;
      __builtin_nontemporal_store(o, (f32x4*)(aout + n0));
    }
    bf16_t* cp = ctx + (size_t)bh * 65536 + (size_t)(q0 + wm * 16 + lg * 4) * 64 + wn * 16 + lr;
#pragma unroll
    for (int r = 0; r < 4; ++r)
      cp[(size_t)r * 64] = (bf16_t)(acc[r] * sL[wm * 16 + lg * 4 + r]);
  }
}

// ---------------- LayerNorm in place on d_out rows ----------------
__global__ __launch_bounds__(256) void ln_kernel(float* __restrict__ io,
                                                 const float* __restrict__ gamma,
                                                 const float* __restrict__ beta) {
  int row = blockIdx.x;
  int t = threadIdx.x;
  float* p = io + (size_t)row * 1024;
  f32x4 v = *(const f32x4*)(p + t * 4);
  float s = v[0] + v[1] + v[2] + v[3];
  float s2 = v[0] * v[0] + v[1] * v[1] + v[2] * v[2] + v[3] * v[3];
#pragma unroll
  for (int off = 1; off <= 32; off <<= 1) {
    s += __shfl_xor(s, off);
    s2 += __shfl_xor(s2, off);
  }
  __shared__ float ps[4], ps2[4];
  int w = t >> 6, l = t & 63;
  if (l == 0) { ps[w] = s; ps2[w] = s2; }
  __syncthreads();
  float S = ps[0] + ps[1] + ps[2] + ps[3];
  float S2 = ps2[0] + ps2[1] + ps2[2] + ps2[3];
  float mu = S * (1.f / 1024.f);
  float var = S2 * (1.f / 1024.f) - mu * mu;
  float rs = rsqrtf(var + 1e-5f);
  f32x4 g = *(const f32x4*)(gamma + t * 4);
  f32x4 b = *(const f32x4*)(beta + t * 4);
  f32x4 o;
  o[0] = (v[0] - mu) * rs * g[0] + b[0];
  o[1] = (v[1] - mu) * rs * g[1] + b[1];
  o[2] = (v[2] - mu) * rs * g[2] + b[2];
  o[3] = (v[3] - mu) * rs * g[3] + b[3];
  *(f32x4*)(p + t * 4) = o;
}

extern "C" void kernel_launch(void* const* d_in, const int* in_sizes, int n_in,
                              void* d_out, int out_size, void* d_ws, size_t ws_size,
                              hipStream_t stream) {
  const float* x = (const float*)d_in[0];
  const float* Wq = (const float*)d_in[1];
  const float* bq = (const float*)d_in[2];
  const float* Wk = (const float*)d_in[3];
  const float* bk = (const float*)d_in[4];
  const float* Wv = (const float*)d_in[5];
  const float* bv = (const float*)d_in[6];
  const float* Wo = (const float*)d_in[7];
  const float* bo = (const float*)d_in[8];
  const float* gamma = (const float*)d_in[9];
  const float* beta = (const float*)d_in[10];

  char* ws = (char*)d_ws;
  size_t off = 0;
  bf16_t* xb = (bf16_t*)(ws + off);  off += (size_t)M_ * D_ * 2;
  bf16_t* Wqb = (bf16_t*)(ws + off); off += (size_t)D_ * D_ * 2;
  bf16_t* Wkb = (bf16_t*)(ws + off); off += (size_t)D_ * D_ * 2;
  bf16_t* Wvb = (bf16_t*)(ws + off); off += (size_t)D_ * D_ * 2;
  bf16_t* Wob = (bf16_t*)(ws + off); off += (size_t)D_ * D_ * 2;
  bf16_t* Qb = (bf16_t*)(ws + off);  off += (size_t)M_ * D_ * 2;
  bf16_t* Kb = (bf16_t*)(ws + off);  off += (size_t)M_ * D_ * 2;
  bf16_t* Vb = (bf16_t*)(ws + off);  off += (size_t)M_ * D_ * 2;
  bf16_t* Vtb = (bf16_t*)(ws + off); off += (size_t)M_ * D_ * 2;
  bf16_t* ctxb = (bf16_t*)(ws + off); off += (size_t)M_ * D_ * 2;

  float* out0 = (float*)d_out;
  float* alpha = out0 + (size_t)M_ * D_;

  cvt_all<<<6144, 256, 0, stream>>>(x, Wq, Wk, Wv, Wo, xb, Wqb, Wkb, Wvb, Wob);

  gemm_qkv2<<<768, 512, 0, stream>>>(xb, Wqb, Wkb, Wvb, bq, bk, bv, Qb, Kb, Vb);
  transpose_v<<<1024, 256, 0, stream>>>(Vb, Vtb);
  attn_kernel<<<4096, 512, 0, stream>>>(Qb, Kb, Vtb, alpha, ctxb);
  gemm_proj2<<<256, 512, 0, stream>>>(ctxb, Wob, bo, x, out0);
  ln_kernel<<<8192, 256, 0, stream>>>(out0, gamma, beta);
}

// Round 11
// 318.438 us; speedup vs baseline: 6.7274x; 1.0014x over previous
//
#include <hip/hip_runtime.h>
#include <stdint.h>
#include <math.h>

typedef __bf16 bf16_t;
typedef float f32x4 __attribute__((ext_vector_type(4)));
typedef __bf16 bf16x8 __attribute__((ext_vector_type(8)));
typedef __bf16 bf16x4 __attribute__((ext_vector_type(4)));

#define D_ 1024
#define M_ 8192

__device__ __forceinline__ f32x4 mfma16(bf16x8 a, bf16x8 b, f32x4 c) {
  return __builtin_amdgcn_mfma_f32_16x16x32_bf16(a, b, c, 0, 0, 0);
}

__device__ __forceinline__ void gl_lds16(const bf16_t* g, bf16_t* l) {
  __builtin_amdgcn_global_load_lds(
      (const __attribute__((address_space(1))) unsigned int*)g,
      (__attribute__((address_space(3))) unsigned int*)l, 16, 0, 0);
}

// ---------------- all fp32 -> bf16 converts in ONE launch ----------------
__global__ __launch_bounds__(256) void cvt_all(
    const float* __restrict__ x,
    const float* __restrict__ w0, const float* __restrict__ w1,
    const float* __restrict__ w2, const float* __restrict__ w3,
    bf16_t* __restrict__ xb,
    bf16_t* __restrict__ d0, bf16_t* __restrict__ d1,
    bf16_t* __restrict__ d2, bf16_t* __restrict__ d3) {
  int b = blockIdx.x;
  const float* s;
  bf16_t* d;
  int i;
  if (b < 4096) {
    s = x; d = xb; i = b * 256 + threadIdx.x;
  } else {
    int g = b - 4096;
    int which = g >> 9;
    s = which == 0 ? w0 : which == 1 ? w1 : which == 2 ? w2 : w3;
    d = which == 0 ? d0 : which == 1 ? d1 : which == 2 ? d2 : d3;
    i = (g & 511) * 256 + threadIdx.x;
  }
  const f32x4* p = (const f32x4*)(s + (size_t)i * 8);
  f32x4 a = p[0], bb = p[1];
  bf16x8 o;
  o[0] = (bf16_t)a.x; o[1] = (bf16_t)a.y; o[2] = (bf16_t)a.z; o[3] = (bf16_t)a.w;
  o[4] = (bf16_t)bb.x; o[5] = (bf16_t)bb.y; o[6] = (bf16_t)bb.z; o[7] = (bf16_t)bb.w;
  *(bf16x8*)(d + (size_t)i * 8) = o;
}

// ============ shared 3-deep 128x256xBK64 pipelined core =============
// 3 LDS buffers (144 KiB): stage kt+2 while computing kt; steady-state wait
// is vmcnt(6) (6 loads of kt+2 stay in flight), vmcnt(0) only at kt=14.
// Zero-conflict XOR slot swizzle (verified R8): phys slot = logical ^ (row&7).
#define LDSB(e) (*(const bf16x8*)(Sm + (e)))

#define STG26(b, kt)                                                          \
  {                                                                           \
    _Pragma("unroll") for (int c = 0; c < 2; ++c)                             \
        gl_lds16(Ap + (size_t)(m0 + c * 64 + srow) * 1024 + (kt) * 64 + scol, \
                 Sm + (b) * 24576 + c * 4096 + tid * 8);                      \
    _Pragma("unroll") for (int c = 0; c < 4; ++c)                             \
        gl_lds16(Bp + (size_t)(n0 + c * 64 + srow) * 1024 + (kt) * 64 + scol, \
                 Sm + (b) * 24576 + 8192 + c * 4096 + tid * 8);               \
  }

__device__ __forceinline__ void core_128x256(const bf16_t* __restrict__ Ap,
                                             const bf16_t* __restrict__ Bp,
                                             int m0, int n0, bf16_t* Sm,
                                             f32x4 acc[4][4]) {
  const int tid = threadIdx.x;
  const int l = tid & 63, w = tid >> 6;
  const int wm = w >> 2, wn = w & 3;
  const int lr = l & 15, lg = l >> 4;
  const int scol = ((l & 7) ^ ((l >> 3) & 7)) * 8;
  const int srow = tid >> 3;  // 0..63
  const int rdA = (wm * 64 + lr) * 64 + (lg ^ (lr & 7)) * 8;
  const int rdB = 8192 + (wn * 64 + lr) * 64 + (lg ^ (lr & 7)) * 8;

  STG26(0, 0)
  STG26(1, 1)
  asm volatile("s_waitcnt vmcnt(6)" ::: "memory");  // kt0 ready, kt1 in flight
  __builtin_amdgcn_sched_barrier(0);
  __builtin_amdgcn_s_barrier();

  for (int kt = 0; kt < 16; ++kt) {
    if (kt + 2 < 16) STG26((kt + 2) % 3, kt + 2)
    const int bb = (kt % 3) * 24576;
    bf16x8 bfr[4][2];
#pragma unroll
    for (int fn = 0; fn < 4; ++fn) {
      bfr[fn][0] = LDSB(bb + rdB + fn * 1024);
      bfr[fn][1] = LDSB((bb + rdB + fn * 1024) ^ 32);
    }
#pragma unroll
    for (int fm = 0; fm < 4; ++fm) {
      bf16x8 a0 = LDSB(bb + rdA + fm * 1024);
      bf16x8 a1 = LDSB((bb + rdA + fm * 1024) ^ 32);
#pragma unroll
      for (int fn = 0; fn < 4; ++fn) {
        acc[fm][fn] = mfma16(a0, bfr[fn][0], acc[fm][fn]);
        acc[fm][fn] = mfma16(a1, bfr[fn][1], acc[fm][fn]);
      }
    }
    if (kt <= 13) {
      asm volatile("s_waitcnt vmcnt(6)" ::: "memory");  // kt+1 ready
    } else if (kt == 14) {
      asm volatile("s_waitcnt vmcnt(0)" ::: "memory");  // kt15 ready
    }
    __builtin_amdgcn_sched_barrier(0);
    __builtin_amdgcn_s_barrier();
  }
}

// ---------------- QKV: 768 blocks = 3.0 dispatch waves ----------------
// which==2 (V) writes TRANSPOSED Vt[bh][dh][s] directly (fuses transpose_v).
__global__ __launch_bounds__(512) void gemm_qkv2(
    const bf16_t* __restrict__ A,
    const bf16_t* __restrict__ Wq, const bf16_t* __restrict__ Wk,
    const bf16_t* __restrict__ Wv,
    const float* __restrict__ bq, const float* __restrict__ bk,
    const float* __restrict__ bv,
    bf16_t* __restrict__ Oq, bf16_t* __restrict__ Ok, bf16_t* __restrict__ Vt) {
  __shared__ bf16_t Sm[73728];  // 144 KiB (3 bufs)

  int wg = blockIdx.x;
  int xcd = wg & 7, local = wg >> 3;          // local 0..95
  int bm = xcd * 8 + (local & 7);             // 0..63
  int bnid = local >> 3;                      // 0..11
  int which = bnid >> 2;
  const bf16_t* Wsel = which == 0 ? Wq : (which == 1 ? Wk : Wv);
  const float* bias = which == 0 ? bq : (which == 1 ? bk : bv);
  const float scale = which == 0 ? 0.18033688f : 1.0f;  // 0.125*log2(e) on Q
  const int m0 = bm * 128, n0 = (bnid & 3) * 256;

  f32x4 acc[4][4] = {};
  core_128x256(A, Wsel, m0, n0, Sm, acc);

  const int tid = threadIdx.x;
  const int l = tid & 63, w = tid >> 6;
  const int wm = w >> 2, wn = w & 3;
  const int lr = l & 15, lg = l >> 4;

  if (which == 2) {
    // V: write transposed. col -> (h, dh); row -> (b, s); 4 consecutive s.
#pragma unroll
    for (int fn = 0; fn < 4; ++fn) {
      int col = n0 + wn * 64 + fn * 16 + lr;
      float bb2 = bias[col];
      int h = col >> 6, dh = col & 63;
#pragma unroll
      for (int fm = 0; fm < 4; ++fm) {
        int row = m0 + wm * 64 + fm * 16 + lg * 4;
        int b = row >> 10, s = row & 1023;
        int bh = b * 16 + h;
        bf16x4 v;
#pragma unroll
        for (int r = 0; r < 4; ++r) v[r] = (bf16_t)(acc[fm][fn][r] + bb2);
        *(bf16x4*)(Vt + (size_t)bh * 65536 + (size_t)dh * 1024 + s) = v;
      }
    }
  } else {
    bf16_t* O = which == 0 ? Oq : Ok;
#pragma unroll
    for (int fn = 0; fn < 4; ++fn) {
      int col = n0 + wn * 64 + fn * 16 + lr;
      float bb2 = bias[col];
#pragma unroll
      for (int fm = 0; fm < 4; ++fm) {
        int row = m0 + wm * 64 + fm * 16 + lg * 4;
        bf16_t* op = O + (size_t)row * 1024 + col;
#pragma unroll
        for (int r = 0; r < 4; ++r)
          op[(size_t)r * 1024] = (bf16_t)((acc[fm][fn][r] + bb2) * scale);
      }
    }
  }
}

// ---------------- proj: 256 blocks = 1.0 wave; fp32 + bias + residual ----------------
__global__ __launch_bounds__(512) void gemm_proj2(
    const bf16_t* __restrict__ A, const bf16_t* __restrict__ W,
    const float* __restrict__ bias, const float* __restrict__ xres,
    float* __restrict__ Out) {
  __shared__ bf16_t Sm[73728];

  int wg = blockIdx.x;
  int xcd = wg & 7, local = wg >> 3;          // 0..31
  int bm = xcd * 8 + (local & 7);             // 0..63
  int bn = local >> 3;                        // 0..3
  const int m0 = bm * 128, n0 = bn * 256;

  f32x4 acc[4][4] = {};
  core_128x256(A, W, m0, n0, Sm, acc);

  const int tid = threadIdx.x;
  const int l = tid & 63, w = tid >> 6;
  const int wm = w >> 2, wn = w & 3;
  const int lr = l & 15, lg = l >> 4;
#pragma unroll
  for (int fn = 0; fn < 4; ++fn) {
    int col = n0 + wn * 64 + fn * 16 + lr;
    float bb2 = bias[col];
#pragma unroll
    for (int fm = 0; fm < 4; ++fm) {
      int row = m0 + wm * 64 + fm * 16 + lg * 4;
#pragma unroll
      for (int r = 0; r < 4; ++r) {
        size_t idx = (size_t)(row + r) * 1024 + col;
        Out[idx] = acc[fm][fn][r] + bb2 + xres[idx];
      }
    }
  }
}

// ---------------- fused attention per (bh, 32-row q tile) ----------------
#define SP_STRIDE 1064
__global__ __launch_bounds__(512, 4) void attn_kernel(
    const bf16_t* __restrict__ Q, const bf16_t* __restrict__ K,
    const bf16_t* __restrict__ Vt, float* __restrict__ alpha,
    bf16_t* __restrict__ ctx) {
  __shared__ bf16_t sP[32][SP_STRIDE];
  __shared__ float sRS[8][32];
  __shared__ float sL[32];

  int id = blockIdx.x;
  int g = id >> 3, x = id & 7;
  int qt = g & 31;
  int bh = ((g >> 5) << 3) | x;
  int q0 = qt * 32;

  const bf16_t* Qb = Q + (size_t)bh * 65536;
  const bf16_t* Kb = K + (size_t)bh * 65536;
  const bf16_t* Vb = Vt + (size_t)bh * 65536;
  float* Ab = alpha + (size_t)bh * 1048576 + (size_t)q0 * 1024;

  int t = threadIdx.x, l = t & 63, w = t >> 6;
  int lr = l & 15, lg = l >> 4;

  bf16x8 qa[2][2];
#pragma unroll
  for (int mi = 0; mi < 2; ++mi)
#pragma unroll
    for (int kk = 0; kk < 2; ++kk)
      qa[mi][kk] = *(const bf16x8*)(Qb + (size_t)(q0 + mi * 16 + lr) * 64 + kk * 32 + lg * 8);

  float pa0 = 0.f, pa1 = 0.f;
#pragma unroll
  for (int tt = 0; tt < 8; ++tt) {
    int n0 = w * 128 + tt * 16;
    bf16x8 kb0 = *(const bf16x8*)(Kb + (size_t)(n0 + lr) * 64 + lg * 8);
    bf16x8 kb1 = *(const bf16x8*)(Kb + (size_t)(n0 + lr) * 64 + 32 + lg * 8);
    f32x4 a0 = {0.f, 0.f, 0.f, 0.f};
    f32x4 a1 = {0.f, 0.f, 0.f, 0.f};
    a0 = mfma16(kb0, qa[0][0], a0);
    a0 = mfma16(kb1, qa[0][1], a0);
    a1 = mfma16(kb0, qa[1][0], a1);
    a1 = mfma16(kb1, qa[1][1], a1);
    bf16x4 w0, w1;
#pragma unroll
    for (int r = 0; r < 4; ++r) {
      float e0 = exp2f(a0[r]);
      float e1 = exp2f(a1[r]);
      pa0 += e0; pa1 += e1;
      w0[r] = (bf16_t)e0;
      w1[r] = (bf16_t)e1;
    }
    *(bf16x4*)&sP[lr][n0 + lg * 4] = w0;
    *(bf16x4*)&sP[16 + lr][n0 + lg * 4] = w1;
  }
  pa0 += __shfl_xor(pa0, 16); pa0 += __shfl_xor(pa0, 32);
  pa1 += __shfl_xor(pa1, 16); pa1 += __shfl_xor(pa1, 32);
  if (l < 16) {
    sRS[w][lr] = pa0;
    sRS[w][16 + lr] = pa1;
  }
  __syncthreads();
  if (t < 32) {
    float s = 0.f;
#pragma unroll
    for (int ww = 0; ww < 8; ++ww) s += sRS[ww][t];
    sL[t] = 1.0f / s;
  }
  __syncthreads();

  {
    int wm = w >> 2, wn = w & 3;
    f32x4 acc = {0.f, 0.f, 0.f, 0.f};
    const bf16_t* vp = Vb + (size_t)(wn * 16 + lr) * 1024 + lg * 8;
    const bf16_t* pp = &sP[wm * 16 + lr][lg * 8];
    int arow = t >> 4, acol = (t & 15) * 4;
    float inv = sL[arow];
    const bf16_t* ap = &sP[arow][acol];
    float* aout = Ab + (size_t)arow * 1024 + acol;
#pragma unroll 4
    for (int n0 = 0; n0 < 1024; n0 += 64) {
      bf16x8 ea0 = *(const bf16x8*)(pp + n0);
      bf16x8 vb0 = *(const bf16x8*)(vp + n0);
      acc = mfma16(ea0, vb0, acc);
      bf16x8 ea1 = *(const bf16x8*)(pp + n0 + 32);
      bf16x8 vb1 = *(const bf16x8*)(vp + n0 + 32);
      acc = mfma16(ea1, vb1, acc);
      bf16x4 p = *(const bf16x4*)(ap + n0);
      f32x4 o;
      o[0] = (float)p[0] * inv;
      o[1] = (float)p[1] * inv;
      o[2] = (float)p[2] * inv;
      o[3] = (float)p[3] * inv;
      __builtin_nontemporal_store(o, (f32x4*)(aout + n0));
    }
    bf16_t* cp = ctx + (size_t)bh * 65536 + (size_t)(q0 + wm * 16 + lg * 4) * 64 + wn * 16 + lr;
#pragma unroll
    for (int r = 0; r < 4; ++r)
      cp[(size_t)r * 64] = (bf16_t)(acc[r] * sL[wm * 16 + lg * 4 + r]);
  }
}

// ---------------- LayerNorm in place on d_out rows ----------------
__global__ __launch_bounds__(256) void ln_kernel(float* __restrict__ io,
                                                 const float* __restrict__ gamma,
                                                 const float* __restrict__ beta) {
  int row = blockIdx.x;
  int t = threadIdx.x;
  float* p = io + (size_t)row * 1024;
  f32x4 v = *(const f32x4*)(p + t * 4);
  float s = v[0] + v[1] + v[2] + v[3];
  float s2 = v[0] * v[0] + v[1] * v[1] + v[2] * v[2] + v[3] * v[3];
#pragma unroll
  for (int off = 1; off <= 32; off <<= 1) {
    s += __shfl_xor(s, off);
    s2 += __shfl_xor(s2, off);
  }
  __shared__ float ps[4], ps2[4];
  int w = t >> 6, l = t & 63;
  if (l == 0) { ps[w] = s; ps2[w] = s2; }
  __syncthreads();
  float S = ps[0] + ps[1] + ps[2] + ps[3];
  float S2 = ps2[0] + ps2[1] + ps2[2] + ps2[3];
  float mu = S * (1.f / 1024.f);
  float var = S2 * (1.f / 1024.f) - mu * mu;
  float rs = rsqrtf(var + 1e-5f);
  f32x4 g = *(const f32x4*)(gamma + t * 4);
  f32x4 b = *(const f32x4*)(beta + t * 4);
  f32x4 o;
  o[0] = (v[0] - mu) * rs * g[0] + b[0];
  o[1] = (v[1] - mu) * rs * g[1] + b[1];
  o[2] = (v[2] - mu) * rs * g[2] + b[2];
  o[3] = (v[3] - mu) * rs * g[3] + b[3];
  *(f32x4*)(p + t * 4) = o;
}

extern "C" void kernel_launch(void* const* d_in, const int* in_sizes, int n_in,
                              void* d_out, int out_size, void* d_ws, size_t ws_size,
                              hipStream_t stream) {
  const float* x = (const float*)d_in[0];
  const float* Wq = (const float*)d_in[1];
  const float* bq = (const float*)d_in[2];
  const float* Wk = (const float*)d_in[3];
  const float* bk = (const float*)d_in[4];
  const float* Wv = (const float*)d_in[5];
  const float* bv = (const float*)d_in[6];
  const float* Wo = (const float*)d_in[7];
  const float* bo = (const float*)d_in[8];
  const float* gamma = (const float*)d_in[9];
  const float* beta = (const float*)d_in[10];

  char* ws = (char*)d_ws;
  size_t off = 0;
  bf16_t* xb = (bf16_t*)(ws + off);  off += (size_t)M_ * D_ * 2;
  bf16_t* Wqb = (bf16_t*)(ws + off); off += (size_t)D_ * D_ * 2;
  bf16_t* Wkb = (bf16_t*)(ws + off); off += (size_t)D_ * D_ * 2;
  bf16_t* Wvb = (bf16_t*)(ws + off); off += (size_t)D_ * D_ * 2;
  bf16_t* Wob = (bf16_t*)(ws + off); off += (size_t)D_ * D_ * 2;
  bf16_t* Qb = (bf16_t*)(ws + off);  off += (size_t)M_ * D_ * 2;
  bf16_t* Kb = (bf16_t*)(ws + off);  off += (size_t)M_ * D_ * 2;
  bf16_t* Vtb = (bf16_t*)(ws + off); off += (size_t)M_ * D_ * 2;
  bf16_t* ctxb = (bf16_t*)(ws + off); off += (size_t)M_ * D_ * 2;

  float* out0 = (float*)d_out;
  float* alpha = out0 + (size_t)M_ * D_;

  cvt_all<<<6144, 256, 0, stream>>>(x, Wq, Wk, Wv, Wo, xb, Wqb, Wkb, Wvb, Wob);

  gemm_qkv2<<<768, 512, 0, stream>>>(xb, Wqb, Wkb, Wvb, bq, bk, bv, Qb, Kb, Vtb);
  attn_kernel<<<4096, 512, 0, stream>>>(Qb, Kb, Vtb, alpha, ctxb);
  gemm_proj2<<<256, 512, 0, stream>>>(ctxb, Wob, bo, x, out0);
  ln_kernel<<<8192, 256, 0, stream>>>(out0, gamma, beta);
}

// Round 12
// 316.112 us; speedup vs baseline: 6.7770x; 1.0074x over previous
//
#include <hip/hip_runtime.h>
#include <stdint.h>
#include <math.h>

typedef __bf16 bf16_t;
typedef float f32x4 __attribute__((ext_vector_type(4)));
typedef __bf16 bf16x8 __attribute__((ext_vector_type(8)));
typedef __bf16 bf16x4 __attribute__((ext_vector_type(4)));

#define D_ 1024
#define M_ 8192

__device__ __forceinline__ f32x4 mfma16(bf16x8 a, bf16x8 b, f32x4 c) {
  return __builtin_amdgcn_mfma_f32_16x16x32_bf16(a, b, c, 0, 0, 0);
}

__device__ __forceinline__ void gl_lds16(const bf16_t* g, bf16_t* l) {
  __builtin_amdgcn_global_load_lds(
      (const __attribute__((address_space(1))) unsigned int*)g,
      (__attribute__((address_space(3))) unsigned int*)l, 16, 0, 0);
}

// ---------------- all fp32 -> bf16 converts in ONE launch ----------------
__global__ __launch_bounds__(256) void cvt_all(
    const float* __restrict__ x,
    const float* __restrict__ w0, const float* __restrict__ w1,
    const float* __restrict__ w2, const float* __restrict__ w3,
    bf16_t* __restrict__ xb,
    bf16_t* __restrict__ d0, bf16_t* __restrict__ d1,
    bf16_t* __restrict__ d2, bf16_t* __restrict__ d3) {
  int b = blockIdx.x;
  const float* s;
  bf16_t* d;
  int i;
  if (b < 4096) {
    s = x; d = xb; i = b * 256 + threadIdx.x;
  } else {
    int g = b - 4096;
    int which = g >> 9;
    s = which == 0 ? w0 : which == 1 ? w1 : which == 2 ? w2 : w3;
    d = which == 0 ? d0 : which == 1 ? d1 : which == 2 ? d2 : d3;
    i = (g & 511) * 256 + threadIdx.x;
  }
  const f32x4* p = (const f32x4*)(s + (size_t)i * 8);
  f32x4 a = p[0], bb = p[1];
  bf16x8 o;
  o[0] = (bf16_t)a.x; o[1] = (bf16_t)a.y; o[2] = (bf16_t)a.z; o[3] = (bf16_t)a.w;
  o[4] = (bf16_t)bb.x; o[5] = (bf16_t)bb.y; o[6] = (bf16_t)bb.z; o[7] = (bf16_t)bb.w;
  *(bf16x8*)(d + (size_t)i * 8) = o;
}

// ============ shared 2-phase 128x256xBK64 double-buffered core =============
// (R10-proven: vmcnt(0)+barrier per K-tile, absmax 0.03125.)
// Zero-conflict XOR slot swizzle (verified R8): phys slot = logical ^ (row&7);
// linear DMA dest + inverse-permuted global source; reads (lg^(lr&7))*8, ^32.
#define LDSB(e) (*(const bf16x8*)(Sm + (e)))

#define STG26(b, kt)                                                          \
  {                                                                           \
    _Pragma("unroll") for (int c = 0; c < 2; ++c)                             \
        gl_lds16(Ap + (size_t)(m0 + c * 64 + srow) * 1024 + (kt) * 64 + scol, \
                 Sm + (b) * 24576 + c * 4096 + tid * 8);                      \
    _Pragma("unroll") for (int c = 0; c < 4; ++c)                             \
        gl_lds16(Bp + (size_t)(n0 + c * 64 + srow) * 1024 + (kt) * 64 + scol, \
                 Sm + (b) * 24576 + 8192 + c * 4096 + tid * 8);               \
  }

__device__ __forceinline__ void core_128x256(const bf16_t* __restrict__ Ap,
                                             const bf16_t* __restrict__ Bp,
                                             int m0, int n0, bf16_t* Sm,
                                             f32x4 acc[4][4]) {
  const int tid = threadIdx.x;
  const int l = tid & 63, w = tid >> 6;
  const int wm = w >> 2, wn = w & 3;
  const int lr = l & 15, lg = l >> 4;
  const int scol = ((l & 7) ^ ((l >> 3) & 7)) * 8;
  const int srow = tid >> 3;  // 0..63
  const int rdA = (wm * 64 + lr) * 64 + (lg ^ (lr & 7)) * 8;
  const int rdB = 8192 + (wn * 64 + lr) * 64 + (lg ^ (lr & 7)) * 8;

  STG26(0, 0)
  asm volatile("s_waitcnt vmcnt(0)" ::: "memory");
  __builtin_amdgcn_sched_barrier(0);
  __builtin_amdgcn_s_barrier();

  int cur = 0;
  for (int kt = 0; kt < 16; ++kt) {
    if (kt < 15) STG26(cur ^ 1, kt + 1)
    const int bb = cur * 24576;
    bf16x8 bfr[4][2];
#pragma unroll
    for (int fn = 0; fn < 4; ++fn) {
      bfr[fn][0] = LDSB(bb + rdB + fn * 1024);
      bfr[fn][1] = LDSB((bb + rdB + fn * 1024) ^ 32);
    }
#pragma unroll
    for (int fm = 0; fm < 4; ++fm) {
      bf16x8 a0 = LDSB(bb + rdA + fm * 1024);
      bf16x8 a1 = LDSB((bb + rdA + fm * 1024) ^ 32);
#pragma unroll
      for (int fn = 0; fn < 4; ++fn) {
        acc[fm][fn] = mfma16(a0, bfr[fn][0], acc[fm][fn]);
        acc[fm][fn] = mfma16(a1, bfr[fn][1], acc[fm][fn]);
      }
    }
    asm volatile("s_waitcnt vmcnt(0)" ::: "memory");
    __builtin_amdgcn_sched_barrier(0);
    __builtin_amdgcn_s_barrier();
    cur ^= 1;
  }
}

// ---------------- QKV: 768 blocks = 3.0 dispatch waves ----------------
// which==2 (V) writes TRANSPOSED Vt[bh][dh][s] directly (fuses transpose_v).
__global__ __launch_bounds__(512) void gemm_qkv2(
    const bf16_t* __restrict__ A,
    const bf16_t* __restrict__ Wq, const bf16_t* __restrict__ Wk,
    const bf16_t* __restrict__ Wv,
    const float* __restrict__ bq, const float* __restrict__ bk,
    const float* __restrict__ bv,
    bf16_t* __restrict__ Oq, bf16_t* __restrict__ Ok, bf16_t* __restrict__ Vt) {
  __shared__ bf16_t Sm[49152];  // 96 KiB (2 bufs)

  int wg = blockIdx.x;
  int xcd = wg & 7, local = wg >> 3;          // local 0..95
  int bm = xcd * 8 + (local & 7);             // 0..63
  int bnid = local >> 3;                      // 0..11
  int which = bnid >> 2;
  const bf16_t* Wsel = which == 0 ? Wq : (which == 1 ? Wk : Wv);
  const float* bias = which == 0 ? bq : (which == 1 ? bk : bv);
  const float scale = which == 0 ? 0.18033688f : 1.0f;  // 0.125*log2(e) on Q
  const int m0 = bm * 128, n0 = (bnid & 3) * 256;

  f32x4 acc[4][4] = {};
  core_128x256(A, Wsel, m0, n0, Sm, acc);

  const int tid = threadIdx.x;
  const int l = tid & 63, w = tid >> 6;
  const int wm = w >> 2, wn = w & 3;
  const int lr = l & 15, lg = l >> 4;

  if (which == 2) {
    // V: write transposed. col -> (h, dh); row -> (b, s); 4 consecutive s.
#pragma unroll
    for (int fn = 0; fn < 4; ++fn) {
      int col = n0 + wn * 64 + fn * 16 + lr;
      float bb2 = bias[col];
      int h = col >> 6, dh = col & 63;
#pragma unroll
      for (int fm = 0; fm < 4; ++fm) {
        int row = m0 + wm * 64 + fm * 16 + lg * 4;
        int b = row >> 10, s = row & 1023;
        int bh = b * 16 + h;
        bf16x4 v;
#pragma unroll
        for (int r = 0; r < 4; ++r) v[r] = (bf16_t)(acc[fm][fn][r] + bb2);
        *(bf16x4*)(Vt + (size_t)bh * 65536 + (size_t)dh * 1024 + s) = v;
      }
    }
  } else {
    bf16_t* O = which == 0 ? Oq : Ok;
#pragma unroll
    for (int fn = 0; fn < 4; ++fn) {
      int col = n0 + wn * 64 + fn * 16 + lr;
      float bb2 = bias[col];
#pragma unroll
      for (int fm = 0; fm < 4; ++fm) {
        int row = m0 + wm * 64 + fm * 16 + lg * 4;
        bf16_t* op = O + (size_t)row * 1024 + col;
#pragma unroll
        for (int r = 0; r < 4; ++r)
          op[(size_t)r * 1024] = (bf16_t)((acc[fm][fn][r] + bb2) * scale);
      }
    }
  }
}

// ---------------- proj: 256 blocks = 1.0 wave; fp32 + bias + residual ----------------
__global__ __launch_bounds__(512) void gemm_proj2(
    const bf16_t* __restrict__ A, const bf16_t* __restrict__ W,
    const float* __restrict__ bias, const float* __restrict__ xres,
    float* __restrict__ Out) {
  __shared__ bf16_t Sm[49152];

  int wg = blockIdx.x;
  int xcd = wg & 7, local = wg >> 3;          // 0..31
  int bm = xcd * 8 + (local & 7);             // 0..63
  int bn = local >> 3;                        // 0..3
  const int m0 = bm * 128, n0 = bn * 256;

  f32x4 acc[4][4] = {};
  core_128x256(A, W, m0, n0, Sm, acc);

  const int tid = threadIdx.x;
  const int l = tid & 63, w = tid >> 6;
  const int wm = w >> 2, wn = w & 3;
  const int lr = l & 15, lg = l >> 4;
#pragma unroll
  for (int fn = 0; fn < 4; ++fn) {
    int col = n0 + wn * 64 + fn * 16 + lr;
    float bb2 = bias[col];
#pragma unroll
    for (int fm = 0; fm < 4; ++fm) {
      int row = m0 + wm * 64 + fm * 16 + lg * 4;
#pragma unroll
      for (int r = 0; r < 4; ++r) {
        size_t idx = (size_t)(row + r) * 1024 + col;
        Out[idx] = acc[fm][fn][r] + bb2 + xres[idx];
      }
    }
  }
}

// ---------------- fused attention per (bh, 32-row q tile) ----------------
#define SP_STRIDE 1064
__global__ __launch_bounds__(512, 4) void attn_kernel(
    const bf16_t* __restrict__ Q, const bf16_t* __restrict__ K,
    const bf16_t* __restrict__ Vt, float* __restrict__ alpha,
    bf16_t* __restrict__ ctx) {
  __shared__ bf16_t sP[32][SP_STRIDE];
  __shared__ float sRS[8][32];
  __shared__ float sL[32];

  int id = blockIdx.x;
  int g = id >> 3, x = id & 7;
  int qt = g & 31;
  int bh = ((g >> 5) << 3) | x;
  int q0 = qt * 32;

  const bf16_t* Qb = Q + (size_t)bh * 65536;
  const bf16_t* Kb = K + (size_t)bh * 65536;
  const bf16_t* Vb = Vt + (size_t)bh * 65536;
  float* Ab = alpha + (size_t)bh * 1048576 + (size_t)q0 * 1024;

  int t = threadIdx.x, l = t & 63, w = t >> 6;
  int lr = l & 15, lg = l >> 4;

  bf16x8 qa[2][2];
#pragma unroll
  for (int mi = 0; mi < 2; ++mi)
#pragma unroll
    for (int kk = 0; kk < 2; ++kk)
      qa[mi][kk] = *(const bf16x8*)(Qb + (size_t)(q0 + mi * 16 + lr) * 64 + kk * 32 + lg * 8);

  float pa0 = 0.f, pa1 = 0.f;
#pragma unroll
  for (int tt = 0; tt < 8; ++tt) {
    int n0 = w * 128 + tt * 16;
    bf16x8 kb0 = *(const bf16x8*)(Kb + (size_t)(n0 + lr) * 64 + lg * 8);
    bf16x8 kb1 = *(const bf16x8*)(Kb + (size_t)(n0 + lr) * 64 + 32 + lg * 8);
    f32x4 a0 = {0.f, 0.f, 0.f, 0.f};
    f32x4 a1 = {0.f, 0.f, 0.f, 0.f};
    a0 = mfma16(kb0, qa[0][0], a0);
    a0 = mfma16(kb1, qa[0][1], a0);
    a1 = mfma16(kb0, qa[1][0], a1);
    a1 = mfma16(kb1, qa[1][1], a1);
    bf16x4 w0, w1;
#pragma unroll
    for (int r = 0; r < 4; ++r) {
      float e0 = exp2f(a0[r]);
      float e1 = exp2f(a1[r]);
      pa0 += e0; pa1 += e1;
      w0[r] = (bf16_t)e0;
      w1[r] = (bf16_t)e1;
    }
    *(bf16x4*)&sP[lr][n0 + lg * 4] = w0;
    *(bf16x4*)&sP[16 + lr][n0 + lg * 4] = w1;
  }
  pa0 += __shfl_xor(pa0, 16); pa0 += __shfl_xor(pa0, 32);
  pa1 += __shfl_xor(pa1, 16); pa1 += __shfl_xor(pa1, 32);
  if (l < 16) {
    sRS[w][lr] = pa0;
    sRS[w][16 + lr] = pa1;
  }
  __syncthreads();
  if (t < 32) {
    float s = 0.f;
#pragma unroll
    for (int ww = 0; ww < 8; ++ww) s += sRS[ww][t];
    sL[t] = 1.0f / s;
  }
  __syncthreads();

  {
    int wm = w >> 2, wn = w & 3;
    f32x4 acc = {0.f, 0.f, 0.f, 0.f};
    const bf16_t* vp = Vb + (size_t)(wn * 16 + lr) * 1024 + lg * 8;
    const bf16_t* pp = &sP[wm * 16 + lr][lg * 8];
    int arow = t >> 4, acol = (t & 15) * 4;
    float inv = sL[arow];
    const bf16_t* ap = &sP[arow][acol];
    float* aout = Ab + (size_t)arow * 1024 + acol;
#pragma unroll 4
    for (int n0 = 0; n0 < 1024; n0 += 64) {
      bf16x8 ea0 = *(const bf16x8*)(pp + n0);
      bf16x8 vb0 = *(const bf16x8*)(vp + n0);
      acc = mfma16(ea0, vb0, acc);
      bf16x8 ea1 = *(const bf16x8*)(pp + n0 + 32);
      bf16x8 vb1 = *(const bf16x8*)(vp + n0 + 32);
      acc = mfma16(ea1, vb1, acc);
      bf16x4 p = *(const bf16x4*)(ap + n0);
      f32x4 o;
      o[0] = (float)p[0] * inv;
      o[1] = (float)p[1] * inv;
      o[2] = (float)p[2] * inv;
      o[3] = (float)p[3] * inv;
      __builtin_nontemporal_store(o, (f32x4*)(aout + n0));
    }
    bf16_t* cp = ctx + (size_t)bh * 65536 + (size_t)(q0 + wm * 16 + lg * 4) * 64 + wn * 16 + lr;
#pragma unroll
    for (int r = 0; r < 4; ++r)
      cp[(size_t)r * 64] = (bf16_t)(acc[r] * sL[wm * 16 + lg * 4 + r]);
  }
}

// ---------------- LayerNorm in place on d_out rows ----------------
__global__ __launch_bounds__(256) void ln_kernel(float* __restrict__ io,
                                                 const float* __restrict__ gamma,
                                                 const float* __restrict__ beta) {
  int row = blockIdx.x;
  int t = threadIdx.x;
  float* p = io + (size_t)row * 1024;
  f32x4 v = *(const f32x4*)(p + t * 4);
  float s = v[0] + v[1] + v[2] + v[3];
  float s2 = v[0] * v[0] + v[1] * v[1] + v[2] * v[2] + v[3] * v[3];
#pragma unroll
  for (int off = 1; off <= 32; off <<= 1) {
    s += __shfl_xor(s, off);
    s2 += __shfl_xor(s2, off);
  }
  __shared__ float ps[4], ps2[4];
  int w = t >> 6, l = t & 63;
  if (l == 0) { ps[w] = s; ps2[w] = s2; }
  __syncthreads();
  float S = ps[0] + ps[1] + ps[2] + ps[3];
  float S2 = ps2[0] + ps2[1] + ps2[2] + ps2[3];
  float mu = S * (1.f / 1024.f);
  float var = S2 * (1.f / 1024.f) - mu * mu;
  float rs = rsqrtf(var + 1e-5f);
  f32x4 g = *(const f32x4*)(gamma + t * 4);
  f32x4 b = *(const f32x4*)(beta + t * 4);
  f32x4 o;
  o[0] = (v[0] - mu) * rs * g[0] + b[0];
  o[1] = (v[1] - mu) * rs * g[1] + b[1];
  o[2] = (v[2] - mu) * rs * g[2] + b[2];
  o[3] = (v[3] - mu) * rs * g[3] + b[3];
  *(f32x4*)(p + t * 4) = o;
}

extern "C" void kernel_launch(void* const* d_in, const int* in_sizes, int n_in,
                              void* d_out, int out_size, void* d_ws, size_t ws_size,
                              hipStream_t stream) {
  const float* x = (const float*)d_in[0];
  const float* Wq = (const float*)d_in[1];
  const float* bq = (const float*)d_in[2];
  const float* Wk = (const float*)d_in[3];
  const float* bk = (const float*)d_in[4];
  const float* Wv = (const float*)d_in[5];
  const float* bv = (const float*)d_in[6];
  const float* Wo = (const float*)d_in[7];
  const float* bo = (const float*)d_in[8];
  const float* gamma = (const float*)d_in[9];
  const float* beta = (const float*)d_in[10];

  char* ws = (char*)d_ws;
  size_t off = 0;
  bf16_t* xb = (bf16_t*)(ws + off);  off += (size_t)M_ * D_ * 2;
  bf16_t* Wqb = (bf16_t*)(ws + off); off += (size_t)D_ * D_ * 2;
  bf16_t* Wkb = (bf16_t*)(ws + off); off += (size_t)D_ * D_ * 2;
  bf16_t* Wvb = (bf16_t*)(ws + off); off += (size_t)D_ * D_ * 2;
  bf16_t* Wob = (bf16_t*)(ws + off); off += (size_t)D_ * D_ * 2;
  bf16_t* Qb = (bf16_t*)(ws + off);  off += (size_t)M_ * D_ * 2;
  bf16_t* Kb = (bf16_t*)(ws + off);  off += (size_t)M_ * D_ * 2;
  bf16_t* Vtb = (bf16_t*)(ws + off); off += (size_t)M_ * D_ * 2;
  bf16_t* ctxb = (bf16_t*)(ws + off); off += (size_t)M_ * D_ * 2;

  float* out0 = (float*)d_out;
  float* alpha = out0 + (size_t)M_ * D_;

  cvt_all<<<6144, 256, 0, stream>>>(x, Wq, Wk, Wv, Wo, xb, Wqb, Wkb, Wvb, Wob);

  gemm_qkv2<<<768, 512, 0, stream>>>(xb, Wqb, Wkb, Wvb, bq, bk, bv, Qb, Kb, Vtb);
  attn_kernel<<<4096, 512, 0, stream>>>(Qb, Kb, Vtb, alpha, ctxb);
  gemm_proj2<<<256, 512, 0, stream>>>(ctxb, Wob, bo, x, out0);
  ln_kernel<<<8192, 256, 0, stream>>>(out0, gamma, beta);
}